// Round 7
// baseline (431.388 us; speedup 1.0000x reference)
//
#include <hip/hip_runtime.h>

// SemNN — twin-tower masked-pool encoder + classifier.
// B=4096, S=128, D=512, VOCAB=50000, NUM_LABELS=3.
// Confirmed: float inputs bf16 (detector keeps f32 fallback), ids int32,
// masks int-like, OUTPUT f32. ws usage: 8 MB.
//
// Round 15:
//  * r14 post-mortem: enc12 (GEMM1+2 fused) was ~120-130us — WORSE than the
//    two kernels it replaced (~60us). Cause: 16 serial KLOOPs x 4 barriers
//    per block, 1 block/CU, full-weight LDS staging per block, 16x16 wave
//    tile with one acc chain. Fusion concept fine; decomposition wrong.
//  * FIX (enc12 v2): block = 16 rows; 8 waves split the 512 output cols
//    (wave w owns cols w*64..+64, 4 sub-tiles of 16). ONE K-sweep per phase
//    produces the whole X1 row-block; B-frags loaded DIRECTLY from global
//    (8 strided u16 loads per frag; w1/w2 are 512KB, L2-resident) -> no LDS
//    staging, ZERO intra-phase barriers. X1 -> 16.6KB LDS shuffle (1 barrier)
//    -> phase-2 A-frags in 64 VGPR -> X2 in place. 512 independent blocks.
//    Serial depth per block: 2 phases + 1 barrier (was 16 KLOOPs + 64 bars).
//  * pool (164us, BW floor) and gemm3_logits (r14, passed) byte-identical.
//  * Dispatches: memset + pool + enc12 + gemm3_logits.

typedef unsigned short u16;
typedef __attribute__((ext_vector_type(8))) short short8;
typedef __attribute__((ext_vector_type(4))) float f32x4;

__device__ __forceinline__ float bfu2f(u16 u) {
    union { unsigned int i; float f; } v;
    v.i = ((unsigned int)u) << 16;
    return v.f;
}

__device__ __forceinline__ u16 f2bfu(float f) {
    union { float f; unsigned int i; } v;
    v.f = f;
    unsigned int x = v.i;
    x += 0x7fffu + ((x >> 16) & 1u);   // RNE
    return (u16)(x >> 16);
}

// tanh(x) = (e^{2x}-1)/(e^{2x}+1) using hw exp2; |x| clamped so e stays
// finite. ~1e-7 rel error, plenty for bf16-rounded outputs.
__device__ __forceinline__ float fast_tanh(float x) {
    float xc = fminf(fmaxf(x, -15.f), 15.f);
    float e = __builtin_amdgcn_exp2f(xc * 2.885390082f);  // 2*log2(e)*x
    return (e - 1.f) / (e + 1.f);
}

// Wave-collective dtype detection; every lane returns flags:
//   bit0: float tensors are bf16 (vs f32); bits2-3: mask type
//   0=int32, 1=byte-bool, 2=bf16, 3=f32
__device__ __forceinline__ int detect_wave(const u16* __restrict__ W,
                                           const unsigned int* __restrict__ m,
                                           int lane)
{
    int cnt = 0;
    int w01 = 1, b01 = 1, lo16 = 0;
    #pragma unroll
    for (int j = lane; j < 256; j += 64) {
        u16 u = W[1024 + 2 * j];
        int e = (u >> 7) & 0xFF;
        cnt += (e >= 0x6A && e <= 0x7E) ? 1 : 0;
        unsigned int v = m[j];
        w01 &= (v <= 1u) ? 1 : 0;
        b01 &= ((v & ~0x01010101u) == 0u) ? 1 : 0;
        lo16 |= ((v & 0xFFFFu) == 0x3F80u) ? 1 : 0;
    }
    #pragma unroll
    for (int off = 32; off > 0; off >>= 1) {
        cnt  += __shfl_down(cnt, off);
        w01  &= __shfl_down(w01, off);
        b01  &= __shfl_down(b01, off);
        lo16 |= __shfl_down(lo16, off);
    }
    int mtype;
    if (w01)        mtype = 0;
    else if (b01)   mtype = 1;
    else if (lo16)  mtype = 2;
    else            mtype = 3;
    int fl = ((cnt >= 128) ? 1 : 0) | (mtype << 2);
    return __shfl(fl, 0);
}

__device__ __forceinline__ int mask_nonzero(const void* __restrict__ msk,
                                            int idx, int mtype)
{
    switch (mtype) {
        case 0:  return ((const int*)msk)[idx] != 0;
        case 1:  return ((const unsigned char*)msk)[idx] != 0;
        case 2:  return ((const u16*)msk)[idx] != 0;
        default: return ((const unsigned int*)msk)[idx] != 0u;
    }
}

// ---------------------------------------------------------------------------
// Kernel 1: embedding gather + masked sum-pool for BOTH sides -> P [8192,512].
// UNCHANGED: measured 164us / 3.2 TB/s / FETCH = logical min.
// ---------------------------------------------------------------------------
__global__ __launch_bounds__(128) void pool_kernel(
    const int* __restrict__ ids_a, const int* __restrict__ ids_b,
    const void* __restrict__ mska, const void* __restrict__ mskb,
    const void* __restrict__ W, u16* __restrict__ P,
    const unsigned int* __restrict__ Mdet)
{
    __shared__ int s_ids[128];
    __shared__ int s_cnt;
    __shared__ int s_flags;
    __shared__ float sP[512];
    const int t = threadIdx.x;
    const int w = t >> 6;
    const int lane = t & 63;

    if (t == 0) s_cnt = 0;
    if (t < 64) {
        int fl = detect_wave((const u16*)W, Mdet, t);
        if (t == 0) s_flags = fl;
    }
    __syncthreads();
    const int  flags = s_flags;
    const bool isbf  = (flags & 1) != 0;
    const int  mtype = (flags >> 2) & 3;

    const int row = blockIdx.x;            // 0..8191
    const int r   = row & 4095;
    const int* __restrict__ ids = (row < 4096) ? ids_a : ids_b;
    const void* __restrict__ msk = (row < 4096) ? mska : mskb;

    int id = ids[r * 128 + t];
    int mk = mask_nonzero(msk, r * 128 + t, mtype);
    if (mk) {
        int idx = atomicAdd(&s_cnt, 1);
        s_ids[idx] = id;
    }
    __syncthreads();
    const int cnt = s_cnt;

    float acc[8] = {};
    if (isbf) {
        const u16* Wb = (const u16*)W;
        int j = w;
        for (; j + 6 < cnt; j += 8) {
            union { uint4 v; u16 s[8]; } r0, r1, r2, r3;
            r0.v = *(const uint4*)(Wb + (size_t)s_ids[j + 0] * 512 + lane * 8);
            r1.v = *(const uint4*)(Wb + (size_t)s_ids[j + 2] * 512 + lane * 8);
            r2.v = *(const uint4*)(Wb + (size_t)s_ids[j + 4] * 512 + lane * 8);
            r3.v = *(const uint4*)(Wb + (size_t)s_ids[j + 6] * 512 + lane * 8);
            #pragma unroll
            for (int i = 0; i < 8; ++i)
                acc[i] += bfu2f(r0.s[i]) + bfu2f(r1.s[i]) +
                          bfu2f(r2.s[i]) + bfu2f(r3.s[i]);
        }
        for (; j < cnt; j += 2) {
            union { uint4 v; u16 s[8]; } rr;
            rr.v = *(const uint4*)(Wb + (size_t)s_ids[j] * 512 + lane * 8);
            #pragma unroll
            for (int i = 0; i < 8; ++i) acc[i] += bfu2f(rr.s[i]);
        }
    } else {
        const float* Wf = (const float*)W;
        for (int j = w; j < cnt; j += 2) {
            const float* rp = Wf + (size_t)s_ids[j] * 512 + lane * 8;
            float4 a = *(const float4*)(rp + 0);
            float4 b = *(const float4*)(rp + 4);
            acc[0] += a.x; acc[1] += a.y; acc[2] += a.z; acc[3] += a.w;
            acc[4] += b.x; acc[5] += b.y; acc[6] += b.z; acc[7] += b.w;
        }
    }

    if (w == 0) {
        #pragma unroll
        for (int i = 0; i < 8; ++i) sP[lane * 8 + i] = acc[i];
    }
    __syncthreads();
    if (w == 1) {
        union { uint4 v; u16 s[8]; } o;
        #pragma unroll
        for (int i = 0; i < 8; ++i)
            o.s[i] = f2bfu(acc[i] + sP[lane * 8 + i]);
        *(uint4*)(P + (size_t)row * 512 + lane * 8) = o.v;
    }
}

// ---------------------------------------------------------------------------
// Kernel 2: enc12 v2 — X2 = tanh(tanh(P@w1+b1)@w2+b2), in place over P.
// 512 blocks x 512 threads; block owns 16 rows R0=bid*16..+16.
// Wave w owns cols [w*64, w*64+64) as 4 sub-tiles of 16. Per phase: ONE
// K-sweep (16 chunks of 32), A-frag 16B load from P rows (L2/L3-hot),
// B-frags gathered directly from global weights (8 strided u16 loads each;
// weights 512KB = L2-resident). No LDS staging, no intra-phase barriers.
// Index math identical to verified r10 MFMA usage:
//   A-frag row=lm, k=kq*8+j;  B-frag col=lm, same k;  C col=lm, row=kq*4+r.
// ---------------------------------------------------------------------------
template<bool ISBF>
__device__ __forceinline__ void enc12_body(
    u16* __restrict__ P,
    const void* __restrict__ w1v, const void* __restrict__ b1v,
    const void* __restrict__ w2v, const void* __restrict__ b2v,
    u16* __restrict__ Xbuf)
{
    const int tid  = threadIdx.x;          // 0..511
    const int lane = tid & 63;
    const int wid  = tid >> 6;             // 0..7
    const int wn64 = wid * 64;             // wave's 64-col slice
    const int lm   = lane & 15;
    const int kq   = lane >> 4;            // 0..3
    const int R0   = blockIdx.x * 16;

    const u16*   b1b = (const u16*)b1v; const float* b1f = (const float*)b1v;
    const u16*   b2b = (const u16*)b2v; const float* b2f = (const float*)b2v;

    // gather one B-frag: col fixed, 8 consecutive k (stride N=512)
#define GATHB(dst, Wb_, Wf_, kbase, col)                                      \
    {                                                                         \
        union { short8 v; u16 s[8]; } u_;                                     \
        if constexpr (ISBF) {                                                 \
            const u16* bp_ = (Wb_) + (size_t)(kbase) * 512 + (col);           \
            _Pragma("unroll")                                                 \
            for (int j_ = 0; j_ < 8; ++j_) u_.s[j_] = bp_[j_ * 512];          \
        } else {                                                              \
            const float* fp_ = (Wf_) + (size_t)(kbase) * 512 + (col);         \
            _Pragma("unroll")                                                 \
            for (int j_ = 0; j_ < 8; ++j_) u_.s[j_] = f2bfu(fp_[j_ * 512]);   \
        }                                                                     \
        dst = u_.v;                                                           \
    }

    // ---- phase 1: X1 row-block in one K-sweep ----
    const u16*   W1b = (const u16*)w1v;  const float* W1f = (const float*)w1v;
    f32x4 acc0 = (f32x4){0.f,0.f,0.f,0.f};
    f32x4 acc1 = (f32x4){0.f,0.f,0.f,0.f};
    f32x4 acc2 = (f32x4){0.f,0.f,0.f,0.f};
    f32x4 acc3 = (f32x4){0.f,0.f,0.f,0.f};
    #pragma unroll 4
    for (int kb = 0; kb < 16; ++kb) {
        const int k0 = kb * 32 + kq * 8;
        short8 a = *(const short8*)(P + (size_t)(R0 + lm) * 512 + k0);
        short8 b0, b1_, b2_, b3;
        GATHB(b0, W1b, W1f, k0, wn64 + 0  + lm)
        GATHB(b1_, W1b, W1f, k0, wn64 + 16 + lm)
        GATHB(b2_, W1b, W1f, k0, wn64 + 32 + lm)
        GATHB(b3, W1b, W1f, k0, wn64 + 48 + lm)
        acc0 = __builtin_amdgcn_mfma_f32_16x16x32_bf16(a, b0, acc0, 0, 0, 0);
        acc1 = __builtin_amdgcn_mfma_f32_16x16x32_bf16(a, b1_, acc1, 0, 0, 0);
        acc2 = __builtin_amdgcn_mfma_f32_16x16x32_bf16(a, b2_, acc2, 0, 0, 0);
        acc3 = __builtin_amdgcn_mfma_f32_16x16x32_bf16(a, b3, acc3, 0, 0, 0);
    }
    // X1 -> Xbuf [16 rows][520] (tanh + bias), C layout col=lm row=kq*4+r
    {
        f32x4* accs[4] = { &acc0, &acc1, &acc2, &acc3 };
        #pragma unroll
        for (int sub = 0; sub < 4; ++sub) {
            const int col = wn64 + sub * 16 + lm;
            const float bia = ISBF ? bfu2f(b1b[col]) : b1f[col];
            #pragma unroll
            for (int r = 0; r < 4; ++r)
                Xbuf[(kq * 4 + r) * 520 + col] =
                    f2bfu(fast_tanh((*accs[sub])[r] + bia));
        }
    }
    __syncthreads();

    // phase-2 A-frags from Xbuf: row=lm, k = s*32 + kq*8
    short8 af2[16];
    #pragma unroll
    for (int s = 0; s < 16; ++s)
        af2[s] = *(const short8*)&Xbuf[lm * 520 + s * 32 + kq * 8];

    // ---- phase 2: X2 row-block, write in place over P ----
    const u16*   W2b = (const u16*)w2v;  const float* W2f = (const float*)w2v;
    acc0 = (f32x4){0.f,0.f,0.f,0.f};
    acc1 = (f32x4){0.f,0.f,0.f,0.f};
    acc2 = (f32x4){0.f,0.f,0.f,0.f};
    acc3 = (f32x4){0.f,0.f,0.f,0.f};
    #pragma unroll 4
    for (int kb = 0; kb < 16; ++kb) {
        const int k0 = kb * 32 + kq * 8;
        short8 b0, b1_, b2_, b3;
        GATHB(b0, W2b, W2f, k0, wn64 + 0  + lm)
        GATHB(b1_, W2b, W2f, k0, wn64 + 16 + lm)
        GATHB(b2_, W2b, W2f, k0, wn64 + 32 + lm)
        GATHB(b3, W2b, W2f, k0, wn64 + 48 + lm)
        acc0 = __builtin_amdgcn_mfma_f32_16x16x32_bf16(af2[kb], b0, acc0, 0, 0, 0);
        acc1 = __builtin_amdgcn_mfma_f32_16x16x32_bf16(af2[kb], b1_, acc1, 0, 0, 0);
        acc2 = __builtin_amdgcn_mfma_f32_16x16x32_bf16(af2[kb], b2_, acc2, 0, 0, 0);
        acc3 = __builtin_amdgcn_mfma_f32_16x16x32_bf16(af2[kb], b3, acc3, 0, 0, 0);
    }
    {
        f32x4* accs[4] = { &acc0, &acc1, &acc2, &acc3 };
        #pragma unroll
        for (int sub = 0; sub < 4; ++sub) {
            const int col = wn64 + sub * 16 + lm;
            const float bia = ISBF ? bfu2f(b2b[col]) : b2f[col];
            #pragma unroll
            for (int r = 0; r < 4; ++r)
                P[(size_t)(R0 + kq * 4 + r) * 512 + col] =
                    f2bfu(fast_tanh((*accs[sub])[r] + bia));
        }
    }
#undef GATHB
}

__global__ __launch_bounds__(512, 2) void enc12_kernel(
    u16* __restrict__ P,
    const void* __restrict__ w1, const void* __restrict__ b1,
    const void* __restrict__ w2, const void* __restrict__ b2,
    const u16* __restrict__ Wdet, const unsigned int* __restrict__ Mdet)
{
    __shared__ __align__(16) u16 Xbuf[16 * 520];     // 16.6 KB
    __shared__ int s_flags;

    if (threadIdx.x < 64) {
        int fl = detect_wave(Wdet, Mdet, threadIdx.x);
        if (threadIdx.x == 0) s_flags = fl;
    }
    __syncthreads();
    if (s_flags & 1) enc12_body<true >(P, w1, b1, w2, b2, Xbuf);
    else             enc12_body<false>(P, w1, b1, w2, b2, Xbuf);
}

// ---------------------------------------------------------------------------
// Kernel 3: GEMM3 + logits (UNCHANGED from r14, passed). H kept in regs;
// logits via shfl-reduce + f32 atomicAdd into memset-zeroed d_out.
// ---------------------------------------------------------------------------
template<bool ISBF>
__device__ __forceinline__ void g3_body(
    const u16* __restrict__ A, const u16* __restrict__ A2, const int K1,
    const void* __restrict__ Bv, const void* __restrict__ biasv,
    const void* __restrict__ w2v, const void* __restrict__ cb2v,
    float* __restrict__ outp, const int K,
    u16* __restrict__ As0, u16* __restrict__ Bs0)
{
    const int tid  = threadIdx.x;
    const int lane = tid & 63;
    const int wid = tid >> 6;
    const int wm  = (wid & 3) * 32;
    const int wn  = (wid >> 2) * 32;
    const int ar = tid >> 2;
    const int ak = (tid & 3) * 8;
    const int bk = tid >> 3;
    const int jn = tid & 7;
    const int nb = jn * 8;
    const int bofs = (((bk >> 3) + jn) & 3) * 8 + (bk & 7);
    const int lm = lane & 15;
    const int kq = lane >> 4;
    const int kc = kq * 8;
    const int m0 = (blockIdx.x & 31) * 128;
    const int n0 = (blockIdx.x >> 5) * 64;

    const u16*   Bb = (const u16*)Bv;
    const float* Bf = (const float*)Bv;

    f32x4 acc[2][2];
    #pragma unroll
    for (int i = 0; i < 2; ++i)
        #pragma unroll
        for (int j = 0; j < 2; ++j)
            acc[i][j] = (f32x4){0.f, 0.f, 0.f, 0.f};

    uint4 ra, rbb;
    float4 rf0, rf1;

#define FETCH(k0)                                                             \
    {                                                                         \
        const int kg = (k0) + ak;                                             \
        const u16* base = (kg < K1) ? (A + kg) : (A2 + (kg - K1));            \
        ra = *(const uint4*)(base + (size_t)(m0 + ar) * 512);                 \
        if (tid < 256) {                                                      \
            if constexpr (ISBF) {                                             \
                rbb = *(const uint4*)(Bb + (size_t)((k0) + bk) * 512 + n0 + nb);\
            } else {                                                          \
                const float* Bp = Bf + (size_t)((k0) + bk) * 512 + n0 + nb;   \
                rf0 = *(const float4*)(Bp + 0);                               \
                rf1 = *(const float4*)(Bp + 4);                               \
            }                                                                 \
        }                                                                     \
    }

#define STORE(pp)                                                             \
    {                                                                         \
        *(uint4*)&As0[(pp) * 5120 + ar * 40 + ak] = ra;                       \
        if (tid < 256) {                                                      \
            u16 bvals[8];                                                     \
            if constexpr (ISBF) {                                             \
                union { uint4 v; u16 s[8]; } ub; ub.v = rbb;                  \
                _Pragma("unroll")                                             \
                for (int i = 0; i < 8; ++i) bvals[i] = ub.s[i];               \
            } else {                                                          \
                bvals[0] = f2bfu(rf0.x); bvals[1] = f2bfu(rf0.y);             \
                bvals[2] = f2bfu(rf0.z); bvals[3] = f2bfu(rf0.w);             \
                bvals[4] = f2bfu(rf1.x); bvals[5] = f2bfu(rf1.y);             \
                bvals[6] = f2bfu(rf1.z); bvals[7] = f2bfu(rf1.w);             \
            }                                                                 \
            _Pragma("unroll")                                                 \
            for (int i = 0; i < 8; ++i)                                       \
                Bs0[(pp) * 2560 + (nb + i) * 40 + bofs] = bvals[i];           \
        }                                                                     \
    }

    FETCH(0)
    STORE(0)
    FETCH(32)
    __syncthreads();

    int p = 0;
    for (int k0 = 0; k0 < K; k0 += 32) {
        if (k0 + 32 < K) {
            STORE(p ^ 1)
            if (k0 + 64 < K) FETCH(k0 + 64)
        }
        const u16* Ap = As0 + p * 5120;
        const u16* Bp2 = Bs0 + p * 2560;
        short8 afr[2], bfr[2];
        #pragma unroll
        for (int i = 0; i < 2; ++i)
            afr[i] = *(const short8*)&Ap[(wm + i * 16 + lm) * 40 + kc];
        #pragma unroll
        for (int j = 0; j < 2; ++j) {
            const int n = wn + j * 16 + lm;
            const int ch = ((kq + (n >> 3)) & 3) * 8;
            bfr[j] = *(const short8*)&Bp2[n * 40 + ch];
        }
        #pragma unroll
        for (int i = 0; i < 2; ++i)
            #pragma unroll
            for (int j = 0; j < 2; ++j)
                acc[i][j] = __builtin_amdgcn_mfma_f32_16x16x32_bf16(
                    afr[i], bfr[j], acc[i][j], 0, 0, 0);
        if (k0 + 32 < K) __syncthreads();
        p ^= 1;
    }
#undef FETCH
#undef STORE

    // epilogue: H = tanh(acc + cb1[n]); logits partials; lm-reduce; atomics
    float lg[2][4][3];
    #pragma unroll
    for (int i = 0; i < 2; ++i)
        #pragma unroll
        for (int r = 0; r < 4; ++r)
            #pragma unroll
            for (int l = 0; l < 3; ++l) lg[i][r][l] = 0.f;

    #pragma unroll
    for (int j = 0; j < 2; ++j) {
        const int n = n0 + wn + j * 16 + lm;
        const float bsv = ISBF ? bfu2f(((const u16*)biasv)[n])
                               : ((const float*)biasv)[n];
        float wc[3];
        #pragma unroll
        for (int l = 0; l < 3; ++l)
            wc[l] = ISBF ? bfu2f(((const u16*)w2v)[n * 3 + l])
                         : ((const float*)w2v)[n * 3 + l];
        #pragma unroll
        for (int i = 0; i < 2; ++i)
            #pragma unroll
            for (int r = 0; r < 4; ++r) {
                const float h = fast_tanh(acc[i][j][r] + bsv);
                #pragma unroll
                for (int l = 0; l < 3; ++l) lg[i][r][l] += h * wc[l];
            }
    }
    // butterfly over the 16 lm lanes (lane bits 0..3)
    #pragma unroll
    for (int off = 1; off <= 8; off <<= 1)
        #pragma unroll
        for (int i = 0; i < 2; ++i)
            #pragma unroll
            for (int r = 0; r < 4; ++r)
                #pragma unroll
                for (int l = 0; l < 3; ++l)
                    lg[i][r][l] += __shfl_xor(lg[i][r][l], off);

    if (lm == 0) {
        const bool addb = (n0 == 0) && (wn == 0);   // exactly one per (m,l)
        float cb[3];
        #pragma unroll
        for (int l = 0; l < 3; ++l)
            cb[l] = ISBF ? bfu2f(((const u16*)cb2v)[l])
                         : ((const float*)cb2v)[l];
        #pragma unroll
        for (int i = 0; i < 2; ++i)
            #pragma unroll
            for (int r = 0; r < 4; ++r) {
                const int m = m0 + wm + i * 16 + kq * 4 + r;
                #pragma unroll
                for (int l = 0; l < 3; ++l) {
                    float v = lg[i][r][l];
                    if (addb) v += cb[l];
                    atomicAdd(&outp[m * 3 + l], v);
                }
            }
    }
}

__global__ __launch_bounds__(512, 2) void gemm3_logits(
    const u16* __restrict__ A, const u16* __restrict__ A2, int K1,
    const void* __restrict__ B, const void* __restrict__ bias,
    const void* __restrict__ w2, const void* __restrict__ cb2,
    float* __restrict__ out, int K,
    const u16* __restrict__ Wdet, const unsigned int* __restrict__ Mdet)
{
    __shared__ __align__(16) u16 As[2 * 128 * 40];
    __shared__ __align__(16) u16 Bs[2 * 64 * 40];
    __shared__ int s_flags;

    if (threadIdx.x < 64) {
        int fl = detect_wave(Wdet, Mdet, threadIdx.x);
        if (threadIdx.x == 0) s_flags = fl;
    }
    __syncthreads();
    if (s_flags & 1)
        g3_body<true >(A, A2, K1, B, bias, w2, cb2, out, K, As, Bs);
    else
        g3_body<false>(A, A2, K1, B, bias, w2, cb2, out, K, As, Bs);
}

// ---------------------------------------------------------------------------
extern "C" void kernel_launch(void* const* d_in, const int* in_sizes, int n_in,
                              void* d_out, int out_size, void* d_ws, size_t ws_size,
                              hipStream_t stream)
{
    const int* ids_a  = (const int*)d_in[0];
    const int* ids_b  = (const int*)d_in[1];
    const void* mask_a = d_in[2];
    const void* mask_b = d_in[3];
    const void* W_emb  = d_in[4];
    const void* enc_w1 = d_in[5];
    const void* enc_b1 = d_in[6];
    const void* enc_w2 = d_in[7];
    const void* enc_b2 = d_in[8];
    const void* cls_w1 = d_in[9];
    const void* cls_b1 = d_in[10];
    const void* cls_w2 = d_in[11];
    const void* cls_b2 = d_in[12];

    const u16* Wdet = (const u16*)W_emb;
    const unsigned int* Mdet = (const unsigned int*)mask_a;

    u16* buf0 = (u16*)d_ws;                          // 8192*512 bf16 = 8 MB
    float* outp = (float*)d_out;

    // logits accumulated via atomicAdd -> zero first (async, graph-safe)
    hipMemsetAsync(d_out, 0, 4096 * 3 * sizeof(float), stream);

    // P -> buf0 (rows 0..4095 side a, 4096..8191 side b)
    pool_kernel<<<8192, 128, 0, stream>>>(ids_a, ids_b, mask_a, mask_b,
                                          W_emb, buf0, Mdet);

    // X2 = tanh(tanh(P@w1+b1)@w2+b2), in place over buf0
    enc12_kernel<<<512, 512, 0, stream>>>(buf0, enc_w1, enc_b1,
                                          enc_w2, enc_b2, Wdet, Mdet);

    // logits = tanh([va|vb]@cw1+cb1) @ cw2 + cb2 -> d_out (f32, atomics)
    gemm3_logits<<<256, 512, 0, stream>>>(
        buf0, buf0 + (size_t)4096 * 512, 512, cls_w1, cls_b1,
        cls_w2, cls_b2, outp, 1024, Wdet, Mdet);
}

// Round 8
// 363.147 us; speedup vs baseline: 1.1879x; 1.1879x over previous
//
#include <hip/hip_runtime.h>

// SemNN — twin-tower masked-pool encoder + classifier.
// B=4096, S=128, D=512, VOCAB=50000, NUM_LABELS=3.
// Confirmed: float inputs bf16 (detector keeps f32 fallback), ids int32,
// masks int-like, OUTPUT f32. ws usage: 16 MB.
//
// Round 16:
//  * r14/r15 post-mortem: every redesign of the GEMM (fused serial-KLOOP,
//    direct-global B-gather) lost to r10's 512-block LDS-staged gemm_mfma.
//    REVERT to r10's GEMM verbatim for g1/g2. Fusion only where the
//    structure is untouched:
//      - logits folded into g3 epilogue (r14 gemm3_logits, passed twice).
//      - d_out zeroing folded into pool (blocks 0..95), removing memset.
//    Dispatches: pool + g1 + g2 + g3L = 4 (r10 had 5), each proven fast.
//  * pool MLP probe: VALUBusy 6% + 3.2TB/s + occupancy 74% => likely
//    latency-bound, not BW-bound. Main loop deepened to 8 in-flight
//    uint4 loads (j+=16). If neutral, pool is at gather floor (info);
//    if MLP-bound, expect ~164 -> ~130us.

typedef unsigned short u16;
typedef __attribute__((ext_vector_type(8))) short short8;
typedef __attribute__((ext_vector_type(4))) float f32x4;

__device__ __forceinline__ float bfu2f(u16 u) {
    union { unsigned int i; float f; } v;
    v.i = ((unsigned int)u) << 16;
    return v.f;
}

__device__ __forceinline__ u16 f2bfu(float f) {
    union { float f; unsigned int i; } v;
    v.f = f;
    unsigned int x = v.i;
    x += 0x7fffu + ((x >> 16) & 1u);   // RNE
    return (u16)(x >> 16);
}

// tanh(x) = (e^{2x}-1)/(e^{2x}+1) using hw exp2; |x| clamped so e stays
// finite. ~1e-7 rel error, plenty for bf16-rounded outputs.
__device__ __forceinline__ float fast_tanh(float x) {
    float xc = fminf(fmaxf(x, -15.f), 15.f);
    float e = __builtin_amdgcn_exp2f(xc * 2.885390082f);  // 2*log2(e)*x
    return (e - 1.f) / (e + 1.f);
}

// Wave-collective dtype detection; every lane returns flags:
//   bit0: float tensors are bf16 (vs f32); bits2-3: mask type
//   0=int32, 1=byte-bool, 2=bf16, 3=f32
__device__ __forceinline__ int detect_wave(const u16* __restrict__ W,
                                           const unsigned int* __restrict__ m,
                                           int lane)
{
    int cnt = 0;
    int w01 = 1, b01 = 1, lo16 = 0;
    #pragma unroll
    for (int j = lane; j < 256; j += 64) {
        u16 u = W[1024 + 2 * j];
        int e = (u >> 7) & 0xFF;
        cnt += (e >= 0x6A && e <= 0x7E) ? 1 : 0;
        unsigned int v = m[j];
        w01 &= (v <= 1u) ? 1 : 0;
        b01 &= ((v & ~0x01010101u) == 0u) ? 1 : 0;
        lo16 |= ((v & 0xFFFFu) == 0x3F80u) ? 1 : 0;
    }
    #pragma unroll
    for (int off = 32; off > 0; off >>= 1) {
        cnt  += __shfl_down(cnt, off);
        w01  &= __shfl_down(w01, off);
        b01  &= __shfl_down(b01, off);
        lo16 |= __shfl_down(lo16, off);
    }
    int mtype;
    if (w01)        mtype = 0;
    else if (b01)   mtype = 1;
    else if (lo16)  mtype = 2;
    else            mtype = 3;
    int fl = ((cnt >= 128) ? 1 : 0) | (mtype << 2);
    return __shfl(fl, 0);
}

__device__ __forceinline__ int mask_nonzero(const void* __restrict__ msk,
                                            int idx, int mtype)
{
    switch (mtype) {
        case 0:  return ((const int*)msk)[idx] != 0;
        case 1:  return ((const unsigned char*)msk)[idx] != 0;
        case 2:  return ((const u16*)msk)[idx] != 0;
        default: return ((const unsigned int*)msk)[idx] != 0u;
    }
}

// ---------------------------------------------------------------------------
// Kernel 1: embedding gather + masked sum-pool for BOTH sides -> P [8192,512].
// 8192 blocks x 128 thr (2 waves). Blocks 0..95 also zero d_out (12288 f32)
// so g3L's atomics land on zeroed memory without a memset dispatch.
// Main loop deepened to 8 in-flight uint4 loads (MLP probe).
// ---------------------------------------------------------------------------
__global__ __launch_bounds__(128) void pool_kernel(
    const int* __restrict__ ids_a, const int* __restrict__ ids_b,
    const void* __restrict__ mska, const void* __restrict__ mskb,
    const void* __restrict__ W, u16* __restrict__ P,
    float* __restrict__ outz,
    const unsigned int* __restrict__ Mdet)
{
    __shared__ int s_ids[128];
    __shared__ int s_cnt;
    __shared__ int s_flags;
    __shared__ float sP[512];
    const int t = threadIdx.x;
    const int w = t >> 6;
    const int lane = t & 63;

    // fold the d_out memset into this dispatch (96*128 = 12288 = 4096*3)
    if (blockIdx.x < 96) outz[blockIdx.x * 128 + t] = 0.f;

    if (t == 0) s_cnt = 0;
    if (t < 64) {
        int fl = detect_wave((const u16*)W, Mdet, t);
        if (t == 0) s_flags = fl;
    }
    __syncthreads();
    const int  flags = s_flags;
    const bool isbf  = (flags & 1) != 0;
    const int  mtype = (flags >> 2) & 3;

    const int row = blockIdx.x;            // 0..8191
    const int r   = row & 4095;
    const int* __restrict__ ids = (row < 4096) ? ids_a : ids_b;
    const void* __restrict__ msk = (row < 4096) ? mska : mskb;

    int id = ids[r * 128 + t];
    int mk = mask_nonzero(msk, r * 128 + t, mtype);
    if (mk) {
        int idx = atomicAdd(&s_cnt, 1);
        s_ids[idx] = id;
    }
    __syncthreads();
    const int cnt = s_cnt;

    float acc[8] = {};
    if (isbf) {
        const u16* Wb = (const u16*)W;
        int j = w;
        // 8-deep MLP main loop (16 tokens per wave-iter)
        for (; j + 14 < cnt; j += 16) {
            union { uint4 v; u16 s[8]; } r0, r1, r2, r3, r4, r5, r6, r7;
            r0.v = *(const uint4*)(Wb + (size_t)s_ids[j + 0]  * 512 + lane * 8);
            r1.v = *(const uint4*)(Wb + (size_t)s_ids[j + 2]  * 512 + lane * 8);
            r2.v = *(const uint4*)(Wb + (size_t)s_ids[j + 4]  * 512 + lane * 8);
            r3.v = *(const uint4*)(Wb + (size_t)s_ids[j + 6]  * 512 + lane * 8);
            r4.v = *(const uint4*)(Wb + (size_t)s_ids[j + 8]  * 512 + lane * 8);
            r5.v = *(const uint4*)(Wb + (size_t)s_ids[j + 10] * 512 + lane * 8);
            r6.v = *(const uint4*)(Wb + (size_t)s_ids[j + 12] * 512 + lane * 8);
            r7.v = *(const uint4*)(Wb + (size_t)s_ids[j + 14] * 512 + lane * 8);
            #pragma unroll
            for (int i = 0; i < 8; ++i)
                acc[i] += ((bfu2f(r0.s[i]) + bfu2f(r1.s[i])) +
                           (bfu2f(r2.s[i]) + bfu2f(r3.s[i]))) +
                          ((bfu2f(r4.s[i]) + bfu2f(r5.s[i])) +
                           (bfu2f(r6.s[i]) + bfu2f(r7.s[i])));
        }
        for (; j + 6 < cnt; j += 8) {
            union { uint4 v; u16 s[8]; } r0, r1, r2, r3;
            r0.v = *(const uint4*)(Wb + (size_t)s_ids[j + 0] * 512 + lane * 8);
            r1.v = *(const uint4*)(Wb + (size_t)s_ids[j + 2] * 512 + lane * 8);
            r2.v = *(const uint4*)(Wb + (size_t)s_ids[j + 4] * 512 + lane * 8);
            r3.v = *(const uint4*)(Wb + (size_t)s_ids[j + 6] * 512 + lane * 8);
            #pragma unroll
            for (int i = 0; i < 8; ++i)
                acc[i] += bfu2f(r0.s[i]) + bfu2f(r1.s[i]) +
                          bfu2f(r2.s[i]) + bfu2f(r3.s[i]);
        }
        for (; j < cnt; j += 2) {
            union { uint4 v; u16 s[8]; } rr;
            rr.v = *(const uint4*)(Wb + (size_t)s_ids[j] * 512 + lane * 8);
            #pragma unroll
            for (int i = 0; i < 8; ++i) acc[i] += bfu2f(rr.s[i]);
        }
    } else {
        const float* Wf = (const float*)W;
        for (int j = w; j < cnt; j += 2) {
            const float* rp = Wf + (size_t)s_ids[j] * 512 + lane * 8;
            float4 a = *(const float4*)(rp + 0);
            float4 b = *(const float4*)(rp + 4);
            acc[0] += a.x; acc[1] += a.y; acc[2] += a.z; acc[3] += a.w;
            acc[4] += b.x; acc[5] += b.y; acc[6] += b.z; acc[7] += b.w;
        }
    }

    if (w == 0) {
        #pragma unroll
        for (int i = 0; i < 8; ++i) sP[lane * 8 + i] = acc[i];
    }
    __syncthreads();
    if (w == 1) {
        union { uint4 v; u16 s[8]; } o;
        #pragma unroll
        for (int i = 0; i < 8; ++i)
            o.s[i] = f2bfu(acc[i] + sP[lane * 8 + i]);
        *(uint4*)(P + (size_t)row * 512 + lane * 8) = o.v;
    }
}

// ---------------------------------------------------------------------------
// GEMM tile (r10 verified, byte-identical): bf16 MFMA + bias + tanh.
// C[m0:+128, n0:+64] over K, N fixed 512. 512 thr (8 waves 4m x 2n, wave
// 32x32), BK=32, double-buffered LDS, one barrier per K-step.
// 40-u16 LDS rows, B rotate-swizzle, C/D layout col=lane&15 row=kq*4+r.
// ---------------------------------------------------------------------------
template<bool ISBF>
__device__ __forceinline__ void gemm_tile(
    const u16* __restrict__ A, const u16* __restrict__ A2, const int K1,
    const void* __restrict__ Bv, const void* __restrict__ biasv,
    u16* __restrict__ C, const int K, const int m0, const int n0,
    u16* __restrict__ As0, u16* __restrict__ Bs0)
{
    const int tid  = threadIdx.x;          // 0..511
    const int lane = tid & 63;
    const int wid = tid >> 6;              // 0..7
    const int wm  = (wid & 3) * 32;
    const int wn  = (wid >> 2) * 32;
    const int ar = tid >> 2;               // 0..127, one uint4 of A per thread
    const int ak = (tid & 3) * 8;
    const int bk = tid >> 3;               // B staging: threads 0..255 only
    const int jn = tid & 7;
    const int nb = jn * 8;
    const int bofs = (((bk >> 3) + jn) & 3) * 8 + (bk & 7);
    const int lm = lane & 15;
    const int kq = lane >> 4;
    const int kc = kq * 8;

    const u16*   Bb = (const u16*)Bv;
    const float* Bf = (const float*)Bv;

    f32x4 acc[2][2];
    #pragma unroll
    for (int i = 0; i < 2; ++i)
        #pragma unroll
        for (int j = 0; j < 2; ++j)
            acc[i][j] = (f32x4){0.f, 0.f, 0.f, 0.f};

    uint4 ra, rbb;
    float4 rf0, rf1;

#define FETCH(k0)                                                             \
    {                                                                         \
        const int kg = (k0) + ak;                                             \
        const u16* base = (kg < K1) ? (A + kg) : (A2 + (kg - K1));            \
        ra = *(const uint4*)(base + (size_t)(m0 + ar) * 512);                 \
        if (tid < 256) {                                                      \
            if constexpr (ISBF) {                                             \
                rbb = *(const uint4*)(Bb + (size_t)((k0) + bk) * 512 + n0 + nb);\
            } else {                                                          \
                const float* Bp = Bf + (size_t)((k0) + bk) * 512 + n0 + nb;   \
                rf0 = *(const float4*)(Bp + 0);                               \
                rf1 = *(const float4*)(Bp + 4);                               \
            }                                                                 \
        }                                                                     \
    }

#define STORE(pp)                                                             \
    {                                                                         \
        *(uint4*)&As0[(pp) * 5120 + ar * 40 + ak] = ra;                       \
        if (tid < 256) {                                                      \
            u16 bvals[8];                                                     \
            if constexpr (ISBF) {                                             \
                union { uint4 v; u16 s[8]; } ub; ub.v = rbb;                  \
                _Pragma("unroll")                                             \
                for (int i = 0; i < 8; ++i) bvals[i] = ub.s[i];               \
            } else {                                                          \
                bvals[0] = f2bfu(rf0.x); bvals[1] = f2bfu(rf0.y);             \
                bvals[2] = f2bfu(rf0.z); bvals[3] = f2bfu(rf0.w);             \
                bvals[4] = f2bfu(rf1.x); bvals[5] = f2bfu(rf1.y);             \
                bvals[6] = f2bfu(rf1.z); bvals[7] = f2bfu(rf1.w);             \
            }                                                                 \
            _Pragma("unroll")                                                 \
            for (int i = 0; i < 8; ++i)                                       \
                Bs0[(pp) * 2560 + (nb + i) * 40 + bofs] = bvals[i];           \
        }                                                                     \
    }

    FETCH(0)
    STORE(0)
    FETCH(32)
    __syncthreads();

    int p = 0;
    for (int k0 = 0; k0 < K; k0 += 32) {
        if (k0 + 32 < K) {
            STORE(p ^ 1)
            if (k0 + 64 < K) FETCH(k0 + 64)
        }
        const u16* Ap = As0 + p * 5120;
        const u16* Bp2 = Bs0 + p * 2560;
        short8 afr[2], bfr[2];
        #pragma unroll
        for (int i = 0; i < 2; ++i)
            afr[i] = *(const short8*)&Ap[(wm + i * 16 + lm) * 40 + kc];
        #pragma unroll
        for (int j = 0; j < 2; ++j) {
            const int n = wn + j * 16 + lm;
            const int ch = ((kq + (n >> 3)) & 3) * 8;
            bfr[j] = *(const short8*)&Bp2[n * 40 + ch];
        }
        #pragma unroll
        for (int i = 0; i < 2; ++i)
            #pragma unroll
            for (int j = 0; j < 2; ++j)
                acc[i][j] = __builtin_amdgcn_mfma_f32_16x16x32_bf16(
                    afr[i], bfr[j], acc[i][j], 0, 0, 0);
        if (k0 + 32 < K) __syncthreads();
        p ^= 1;
    }
#undef FETCH
#undef STORE

    // epilogue: bias + tanh + bf16 store
    #pragma unroll
    for (int j = 0; j < 2; ++j) {
        const int n = n0 + wn + j * 16 + lm;
        const float bsv = ISBF ? bfu2f(((const u16*)biasv)[n])
                               : ((const float*)biasv)[n];
        #pragma unroll
        for (int i = 0; i < 2; ++i) {
            #pragma unroll
            for (int r = 0; r < 4; ++r) {
                const int m = m0 + wm + i * 16 + kq * 4 + r;
                C[(size_t)m * 512 + n] = f2bfu(fast_tanh(acc[i][j][r] + bsv));
            }
        }
    }
}

__global__ __launch_bounds__(512, 2) void gemm_mfma(
    const u16* __restrict__ A, const u16* __restrict__ A2, int K1,
    const void* __restrict__ B, const void* __restrict__ bias,
    u16* __restrict__ C, int K,
    const u16* __restrict__ Wdet, const unsigned int* __restrict__ Mdet)
{
    __shared__ __align__(16) u16 As[2 * 128 * 40];
    __shared__ __align__(16) u16 Bs[2 * 64 * 40];
    __shared__ int s_flags;

    if (threadIdx.x < 64) {
        int fl = detect_wave(Wdet, Mdet, threadIdx.x);
        if (threadIdx.x == 0) s_flags = fl;
    }
    __syncthreads();
    const int m0 = blockIdx.x * 128;
    const int n0 = blockIdx.y * 64;
    if (s_flags & 1) gemm_tile<true >(A, A2, K1, B, bias, C, K, m0, n0, As, Bs);
    else             gemm_tile<false>(A, A2, K1, B, bias, C, K, m0, n0, As, Bs);
}

// ---------------------------------------------------------------------------
// Kernel 3: GEMM3 + logits (r14, passed twice). H kept in regs; logits via
// shfl-reduce over lm lanes + f32 atomicAdd into zeroed d_out.
// ---------------------------------------------------------------------------
template<bool ISBF>
__device__ __forceinline__ void g3_body(
    const u16* __restrict__ A, const u16* __restrict__ A2, const int K1,
    const void* __restrict__ Bv, const void* __restrict__ biasv,
    const void* __restrict__ w2v, const void* __restrict__ cb2v,
    float* __restrict__ outp, const int K,
    u16* __restrict__ As0, u16* __restrict__ Bs0)
{
    const int tid  = threadIdx.x;
    const int lane = tid & 63;
    const int wid = tid >> 6;
    const int wm  = (wid & 3) * 32;
    const int wn  = (wid >> 2) * 32;
    const int ar = tid >> 2;
    const int ak = (tid & 3) * 8;
    const int bk = tid >> 3;
    const int jn = tid & 7;
    const int nb = jn * 8;
    const int bofs = (((bk >> 3) + jn) & 3) * 8 + (bk & 7);
    const int lm = lane & 15;
    const int kq = lane >> 4;
    const int kc = kq * 8;
    const int m0 = (blockIdx.x & 31) * 128;
    const int n0 = (blockIdx.x >> 5) * 64;

    const u16*   Bb = (const u16*)Bv;
    const float* Bf = (const float*)Bv;

    f32x4 acc[2][2];
    #pragma unroll
    for (int i = 0; i < 2; ++i)
        #pragma unroll
        for (int j = 0; j < 2; ++j)
            acc[i][j] = (f32x4){0.f, 0.f, 0.f, 0.f};

    uint4 ra, rbb;
    float4 rf0, rf1;

#define FETCH(k0)                                                             \
    {                                                                         \
        const int kg = (k0) + ak;                                             \
        const u16* base = (kg < K1) ? (A + kg) : (A2 + (kg - K1));            \
        ra = *(const uint4*)(base + (size_t)(m0 + ar) * 512);                 \
        if (tid < 256) {                                                      \
            if constexpr (ISBF) {                                             \
                rbb = *(const uint4*)(Bb + (size_t)((k0) + bk) * 512 + n0 + nb);\
            } else {                                                          \
                const float* Bp = Bf + (size_t)((k0) + bk) * 512 + n0 + nb;   \
                rf0 = *(const float4*)(Bp + 0);                               \
                rf1 = *(const float4*)(Bp + 4);                               \
            }                                                                 \
        }                                                                     \
    }

#define STORE(pp)                                                             \
    {                                                                         \
        *(uint4*)&As0[(pp) * 5120 + ar * 40 + ak] = ra;                       \
        if (tid < 256) {                                                      \
            u16 bvals[8];                                                     \
            if constexpr (ISBF) {                                             \
                union { uint4 v; u16 s[8]; } ub; ub.v = rbb;                  \
                _Pragma("unroll")                                             \
                for (int i = 0; i < 8; ++i) bvals[i] = ub.s[i];               \
            } else {                                                          \
                bvals[0] = f2bfu(rf0.x); bvals[1] = f2bfu(rf0.y);             \
                bvals[2] = f2bfu(rf0.z); bvals[3] = f2bfu(rf0.w);             \
                bvals[4] = f2bfu(rf1.x); bvals[5] = f2bfu(rf1.y);             \
                bvals[6] = f2bfu(rf1.z); bvals[7] = f2bfu(rf1.w);             \
            }                                                                 \
            _Pragma("unroll")                                                 \
            for (int i = 0; i < 8; ++i)                                       \
                Bs0[(pp) * 2560 + (nb + i) * 40 + bofs] = bvals[i];           \
        }                                                                     \
    }

    FETCH(0)
    STORE(0)
    FETCH(32)
    __syncthreads();

    int p = 0;
    for (int k0 = 0; k0 < K; k0 += 32) {
        if (k0 + 32 < K) {
            STORE(p ^ 1)
            if (k0 + 64 < K) FETCH(k0 + 64)
        }
        const u16* Ap = As0 + p * 5120;
        const u16* Bp2 = Bs0 + p * 2560;
        short8 afr[2], bfr[2];
        #pragma unroll
        for (int i = 0; i < 2; ++i)
            afr[i] = *(const short8*)&Ap[(wm + i * 16 + lm) * 40 + kc];
        #pragma unroll
        for (int j = 0; j < 2; ++j) {
            const int n = wn + j * 16 + lm;
            const int ch = ((kq + (n >> 3)) & 3) * 8;
            bfr[j] = *(const short8*)&Bp2[n * 40 + ch];
        }
        #pragma unroll
        for (int i = 0; i < 2; ++i)
            #pragma unroll
            for (int j = 0; j < 2; ++j)
                acc[i][j] = __builtin_amdgcn_mfma_f32_16x16x32_bf16(
                    afr[i], bfr[j], acc[i][j], 0, 0, 0);
        if (k0 + 32 < K) __syncthreads();
        p ^= 1;
    }
#undef FETCH
#undef STORE

    // epilogue: H = tanh(acc + cb1[n]); logits partials; lm-reduce; atomics
    float lg[2][4][3];
    #pragma unroll
    for (int i = 0; i < 2; ++i)
        #pragma unroll
        for (int r = 0; r < 4; ++r)
            #pragma unroll
            for (int l = 0; l < 3; ++l) lg[i][r][l] = 0.f;

    #pragma unroll
    for (int j = 0; j < 2; ++j) {
        const int n = n0 + wn + j * 16 + lm;
        const float bsv = ISBF ? bfu2f(((const u16*)biasv)[n])
                               : ((const float*)biasv)[n];
        float wc[3];
        #pragma unroll
        for (int l = 0; l < 3; ++l)
            wc[l] = ISBF ? bfu2f(((const u16*)w2v)[n * 3 + l])
                         : ((const float*)w2v)[n * 3 + l];
        #pragma unroll
        for (int i = 0; i < 2; ++i)
            #pragma unroll
            for (int r = 0; r < 4; ++r) {
                const float h = fast_tanh(acc[i][j][r] + bsv);
                #pragma unroll
                for (int l = 0; l < 3; ++l) lg[i][r][l] += h * wc[l];
            }
    }
    // butterfly over the 16 lm lanes (lane bits 0..3)
    #pragma unroll
    for (int off = 1; off <= 8; off <<= 1)
        #pragma unroll
        for (int i = 0; i < 2; ++i)
            #pragma unroll
            for (int r = 0; r < 4; ++r)
                #pragma unroll
                for (int l = 0; l < 3; ++l)
                    lg[i][r][l] += __shfl_xor(lg[i][r][l], off);

    if (lm == 0) {
        const bool addb = (n0 == 0) && (wn == 0);   // exactly one per (m,l)
        float cb[3];
        #pragma unroll
        for (int l = 0; l < 3; ++l)
            cb[l] = ISBF ? bfu2f(((const u16*)cb2v)[l])
                         : ((const float*)cb2v)[l];
        #pragma unroll
        for (int i = 0; i < 2; ++i)
            #pragma unroll
            for (int r = 0; r < 4; ++r) {
                const int m = m0 + wm + i * 16 + kq * 4 + r;
                #pragma unroll
                for (int l = 0; l < 3; ++l) {
                    float v = lg[i][r][l];
                    if (addb) v += cb[l];
                    atomicAdd(&outp[m * 3 + l], v);
                }
            }
    }
}

__global__ __launch_bounds__(512, 2) void gemm3_logits(
    const u16* __restrict__ A, const u16* __restrict__ A2, int K1,
    const void* __restrict__ B, const void* __restrict__ bias,
    const void* __restrict__ w2, const void* __restrict__ cb2,
    float* __restrict__ out, int K,
    const u16* __restrict__ Wdet, const unsigned int* __restrict__ Mdet)
{
    __shared__ __align__(16) u16 As[2 * 128 * 40];
    __shared__ __align__(16) u16 Bs[2 * 64 * 40];
    __shared__ int s_flags;

    if (threadIdx.x < 64) {
        int fl = detect_wave(Wdet, Mdet, threadIdx.x);
        if (threadIdx.x == 0) s_flags = fl;
    }
    __syncthreads();
    if (s_flags & 1)
        g3_body<true >(A, A2, K1, B, bias, w2, cb2, out, K, As, Bs);
    else
        g3_body<false>(A, A2, K1, B, bias, w2, cb2, out, K, As, Bs);
}

// ---------------------------------------------------------------------------
extern "C" void kernel_launch(void* const* d_in, const int* in_sizes, int n_in,
                              void* d_out, int out_size, void* d_ws, size_t ws_size,
                              hipStream_t stream)
{
    const int* ids_a  = (const int*)d_in[0];
    const int* ids_b  = (const int*)d_in[1];
    const void* mask_a = d_in[2];
    const void* mask_b = d_in[3];
    const void* W_emb  = d_in[4];
    const void* enc_w1 = d_in[5];
    const void* enc_b1 = d_in[6];
    const void* enc_w2 = d_in[7];
    const void* enc_b2 = d_in[8];
    const void* cls_w1 = d_in[9];
    const void* cls_b1 = d_in[10];
    const void* cls_w2 = d_in[11];
    const void* cls_b2 = d_in[12];

    const u16* Wdet = (const u16*)W_emb;
    const unsigned int* Mdet = (const unsigned int*)mask_a;

    u16* buf0 = (u16*)d_ws;                          // 8192*512 bf16 = 8 MB
    u16* buf1 = buf0 + (size_t)8192 * 512;           // 8 MB
    float* outp = (float*)d_out;

    // P -> buf0 (rows 0..4095 side a, 4096..8191 side b); also zeroes d_out
    pool_kernel<<<8192, 128, 0, stream>>>(ids_a, ids_b, mask_a, mask_b,
                                          W_emb, buf0, outp, Mdet);

    // X1 = tanh(P @ w1 + b1) -> buf1
    gemm_mfma<<<dim3(64, 8), 512, 0, stream>>>(
        buf0, buf0, 512, enc_w1, enc_b1, buf1, 512, Wdet, Mdet);

    // X2 = tanh(X1 @ w2 + b2) -> buf0
    gemm_mfma<<<dim3(64, 8), 512, 0, stream>>>(
        buf1, buf1, 512, enc_w2, enc_b2, buf0, 512, Wdet, Mdet);

    // logits = tanh([va|vb]@cw1+cb1) @ cw2 + cb2 -> d_out (f32, atomics)
    gemm3_logits<<<256, 512, 0, stream>>>(
        buf0, buf0 + (size_t)4096 * 512, 512, cls_w1, cls_b1,
        cls_w2, cls_b2, outp, 1024, Wdet, Mdet);
}

// Round 9
// 354.053 us; speedup vs baseline: 1.2184x; 1.0257x over previous
//
#include <hip/hip_runtime.h>

// SemNN — twin-tower masked-pool encoder + classifier.
// B=4096, S=128, D=512, VOCAB=50000, NUM_LABELS=3.
// Confirmed: float inputs bf16 (detector keeps f32 fallback), ids int32,
// masks int-like, OUTPUT f32. ws usage: 16 MB.
//
// Round 17:
//  * r16 post-mortem: removing 2 dispatch boundaries changed nothing
//    (357->363, noise) => dispatch overhead is SMALL; the 3 GEMM dispatches
//    really spend ~180-200us wall at ~1% MfmaUtil. Never-varied knob: the
//    K-step count (always 16 x BK=32). Theory: per-step fixed stall
//    (1-deep prefetch < global latency + the vmcnt(0) drain before each
//    s_barrier) dominates => time ~ steps x C, invariant to waves/barriers
//    — matches all observations.
//  * FIX: BK=64 => 8 steps for g1/g2 (16 for g3), 8 MFMA/wave/step.
//    A staged [128][72]-u16 rows (2 x uint4/thread), B 8-chunk rotate
//    swizzle ([64][72] rows; store slot ((k>>3)+n/8)&7, read chunk h*4+kq)
//    — bank-enumerated: floor (8/bank) with only free 2-way aliasing.
//    Wave layout + MFMA mapping + epilogues byte-identical to r10/r14/r16.
//  * pool: r16 version (159-162us, fabric floor; zeroes d_out inline).
//  * Dispatches: pool + g1 + g2 + g3L = 4.

typedef unsigned short u16;
typedef __attribute__((ext_vector_type(8))) short short8;
typedef __attribute__((ext_vector_type(4))) float f32x4;

__device__ __forceinline__ float bfu2f(u16 u) {
    union { unsigned int i; float f; } v;
    v.i = ((unsigned int)u) << 16;
    return v.f;
}

__device__ __forceinline__ u16 f2bfu(float f) {
    union { float f; unsigned int i; } v;
    v.f = f;
    unsigned int x = v.i;
    x += 0x7fffu + ((x >> 16) & 1u);   // RNE
    return (u16)(x >> 16);
}

// tanh(x) = (e^{2x}-1)/(e^{2x}+1) using hw exp2; |x| clamped so e stays
// finite. ~1e-7 rel error, plenty for bf16-rounded outputs.
__device__ __forceinline__ float fast_tanh(float x) {
    float xc = fminf(fmaxf(x, -15.f), 15.f);
    float e = __builtin_amdgcn_exp2f(xc * 2.885390082f);  // 2*log2(e)*x
    return (e - 1.f) / (e + 1.f);
}

// Wave-collective dtype detection; every lane returns flags:
//   bit0: float tensors are bf16 (vs f32); bits2-3: mask type
//   0=int32, 1=byte-bool, 2=bf16, 3=f32
__device__ __forceinline__ int detect_wave(const u16* __restrict__ W,
                                           const unsigned int* __restrict__ m,
                                           int lane)
{
    int cnt = 0;
    int w01 = 1, b01 = 1, lo16 = 0;
    #pragma unroll
    for (int j = lane; j < 256; j += 64) {
        u16 u = W[1024 + 2 * j];
        int e = (u >> 7) & 0xFF;
        cnt += (e >= 0x6A && e <= 0x7E) ? 1 : 0;
        unsigned int v = m[j];
        w01 &= (v <= 1u) ? 1 : 0;
        b01 &= ((v & ~0x01010101u) == 0u) ? 1 : 0;
        lo16 |= ((v & 0xFFFFu) == 0x3F80u) ? 1 : 0;
    }
    #pragma unroll
    for (int off = 32; off > 0; off >>= 1) {
        cnt  += __shfl_down(cnt, off);
        w01  &= __shfl_down(w01, off);
        b01  &= __shfl_down(b01, off);
        lo16 |= __shfl_down(lo16, off);
    }
    int mtype;
    if (w01)        mtype = 0;
    else if (b01)   mtype = 1;
    else if (lo16)  mtype = 2;
    else            mtype = 3;
    int fl = ((cnt >= 128) ? 1 : 0) | (mtype << 2);
    return __shfl(fl, 0);
}

__device__ __forceinline__ int mask_nonzero(const void* __restrict__ msk,
                                            int idx, int mtype)
{
    switch (mtype) {
        case 0:  return ((const int*)msk)[idx] != 0;
        case 1:  return ((const unsigned char*)msk)[idx] != 0;
        case 2:  return ((const u16*)msk)[idx] != 0;
        default: return ((const unsigned int*)msk)[idx] != 0u;
    }
}

// ---------------------------------------------------------------------------
// Kernel 1: embedding gather + masked sum-pool for BOTH sides -> P [8192,512].
// r16 version (measured 159-162us, fabric floor). Blocks 0..95 zero d_out.
// ---------------------------------------------------------------------------
__global__ __launch_bounds__(128) void pool_kernel(
    const int* __restrict__ ids_a, const int* __restrict__ ids_b,
    const void* __restrict__ mska, const void* __restrict__ mskb,
    const void* __restrict__ W, u16* __restrict__ P,
    float* __restrict__ outz,
    const unsigned int* __restrict__ Mdet)
{
    __shared__ int s_ids[128];
    __shared__ int s_cnt;
    __shared__ int s_flags;
    __shared__ float sP[512];
    const int t = threadIdx.x;
    const int w = t >> 6;
    const int lane = t & 63;

    if (blockIdx.x < 96) outz[blockIdx.x * 128 + t] = 0.f;

    if (t == 0) s_cnt = 0;
    if (t < 64) {
        int fl = detect_wave((const u16*)W, Mdet, t);
        if (t == 0) s_flags = fl;
    }
    __syncthreads();
    const int  flags = s_flags;
    const bool isbf  = (flags & 1) != 0;
    const int  mtype = (flags >> 2) & 3;

    const int row = blockIdx.x;            // 0..8191
    const int r   = row & 4095;
    const int* __restrict__ ids = (row < 4096) ? ids_a : ids_b;
    const void* __restrict__ msk = (row < 4096) ? mska : mskb;

    int id = ids[r * 128 + t];
    int mk = mask_nonzero(msk, r * 128 + t, mtype);
    if (mk) {
        int idx = atomicAdd(&s_cnt, 1);
        s_ids[idx] = id;
    }
    __syncthreads();
    const int cnt = s_cnt;

    float acc[8] = {};
    if (isbf) {
        const u16* Wb = (const u16*)W;
        int j = w;
        for (; j + 14 < cnt; j += 16) {
            union { uint4 v; u16 s[8]; } r0, r1, r2, r3, r4, r5, r6, r7;
            r0.v = *(const uint4*)(Wb + (size_t)s_ids[j + 0]  * 512 + lane * 8);
            r1.v = *(const uint4*)(Wb + (size_t)s_ids[j + 2]  * 512 + lane * 8);
            r2.v = *(const uint4*)(Wb + (size_t)s_ids[j + 4]  * 512 + lane * 8);
            r3.v = *(const uint4*)(Wb + (size_t)s_ids[j + 6]  * 512 + lane * 8);
            r4.v = *(const uint4*)(Wb + (size_t)s_ids[j + 8]  * 512 + lane * 8);
            r5.v = *(const uint4*)(Wb + (size_t)s_ids[j + 10] * 512 + lane * 8);
            r6.v = *(const uint4*)(Wb + (size_t)s_ids[j + 12] * 512 + lane * 8);
            r7.v = *(const uint4*)(Wb + (size_t)s_ids[j + 14] * 512 + lane * 8);
            #pragma unroll
            for (int i = 0; i < 8; ++i)
                acc[i] += ((bfu2f(r0.s[i]) + bfu2f(r1.s[i])) +
                           (bfu2f(r2.s[i]) + bfu2f(r3.s[i]))) +
                          ((bfu2f(r4.s[i]) + bfu2f(r5.s[i])) +
                           (bfu2f(r6.s[i]) + bfu2f(r7.s[i])));
        }
        for (; j + 6 < cnt; j += 8) {
            union { uint4 v; u16 s[8]; } r0, r1, r2, r3;
            r0.v = *(const uint4*)(Wb + (size_t)s_ids[j + 0] * 512 + lane * 8);
            r1.v = *(const uint4*)(Wb + (size_t)s_ids[j + 2] * 512 + lane * 8);
            r2.v = *(const uint4*)(Wb + (size_t)s_ids[j + 4] * 512 + lane * 8);
            r3.v = *(const uint4*)(Wb + (size_t)s_ids[j + 6] * 512 + lane * 8);
            #pragma unroll
            for (int i = 0; i < 8; ++i)
                acc[i] += bfu2f(r0.s[i]) + bfu2f(r1.s[i]) +
                          bfu2f(r2.s[i]) + bfu2f(r3.s[i]);
        }
        for (; j < cnt; j += 2) {
            union { uint4 v; u16 s[8]; } rr;
            rr.v = *(const uint4*)(Wb + (size_t)s_ids[j] * 512 + lane * 8);
            #pragma unroll
            for (int i = 0; i < 8; ++i) acc[i] += bfu2f(rr.s[i]);
        }
    } else {
        const float* Wf = (const float*)W;
        for (int j = w; j < cnt; j += 2) {
            const float* rp = Wf + (size_t)s_ids[j] * 512 + lane * 8;
            float4 a = *(const float4*)(rp + 0);
            float4 b = *(const float4*)(rp + 4);
            acc[0] += a.x; acc[1] += a.y; acc[2] += a.z; acc[3] += a.w;
            acc[4] += b.x; acc[5] += b.y; acc[6] += b.z; acc[7] += b.w;
        }
    }

    if (w == 0) {
        #pragma unroll
        for (int i = 0; i < 8; ++i) sP[lane * 8 + i] = acc[i];
    }
    __syncthreads();
    if (w == 1) {
        union { uint4 v; u16 s[8]; } o;
        #pragma unroll
        for (int i = 0; i < 8; ++i)
            o.s[i] = f2bfu(acc[i] + sP[lane * 8 + i]);
        *(uint4*)(P + (size_t)row * 512 + lane * 8) = o.v;
    }
}

// ---------------------------------------------------------------------------
// GEMM tile, BK=64: C[m0:+128, n0:+64] over K (N fixed 512). 512 thr,
// 8 waves 4m x 2n (wave 32x32, acc 2x2 — SAME mapping/epilogue as r10).
// A LDS [128][72] u16 (unswizzled); B LDS [64 n][72] with 8-chunk rotate:
// store slot ((k>>3)+n/8)&7, read chunk h*4+kq. Double-buffered, one
// barrier per 64-wide K-step => 8 steps (g1/g2), 16 (g3).
// ---------------------------------------------------------------------------
#define GEMM_KLOOP_BK64                                                        \
    FETCH(0)                                                                   \
    STORE(0)                                                                   \
    FETCH(64)                                                                  \
    __syncthreads();                                                           \
    int p = 0;                                                                 \
    for (int k0 = 0; k0 < K; k0 += 64) {                                       \
        if (k0 + 64 < K) {                                                     \
            STORE(p ^ 1)                                                       \
            if (k0 + 128 < K) FETCH(k0 + 128)                                  \
        }                                                                      \
        const u16* Ap  = As0 + p * 9216;                                       \
        const u16* Bp2 = Bs0 + p * 4608;                                       \
        short8 af0[2], af1[2], bf0[2], bf1[2];                                 \
        _Pragma("unroll")                                                      \
        for (int i = 0; i < 2; ++i) {                                          \
            af0[i] = *(const short8*)&Ap[(wm + i * 16 + lm) * 72 + kq * 8];    \
            af1[i] = *(const short8*)&Ap[(wm + i * 16 + lm) * 72 + 32 + kq * 8];\
        }                                                                      \
        _Pragma("unroll")                                                      \
        for (int j = 0; j < 2; ++j) {                                          \
            const int n = wn + j * 16 + lm;                                    \
            bf0[j] = *(const short8*)&Bp2[n * 72 + ((kq + (n >> 3)) & 7) * 8]; \
            bf1[j] = *(const short8*)&Bp2[n * 72 + ((4 + kq + (n >> 3)) & 7) * 8];\
        }                                                                      \
        _Pragma("unroll")                                                      \
        for (int i = 0; i < 2; ++i)                                            \
            _Pragma("unroll")                                                  \
            for (int j = 0; j < 2; ++j) {                                      \
                acc[i][j] = __builtin_amdgcn_mfma_f32_16x16x32_bf16(           \
                    af0[i], bf0[j], acc[i][j], 0, 0, 0);                       \
                acc[i][j] = __builtin_amdgcn_mfma_f32_16x16x32_bf16(           \
                    af1[i], bf1[j], acc[i][j], 0, 0, 0);                       \
            }                                                                  \
        if (k0 + 64 < K) __syncthreads();                                      \
        p ^= 1;                                                                \
    }

#define GEMM_FETCH_STORE_BK64                                                  \
    uint4 ra0, ra1, rbb;                                                       \
    float4 rf0, rf1;                                                           \
    (void)rf0; (void)rf1;

#define FETCH(k0)                                                             \
    {                                                                         \
        const int kg = (k0) + ac;                                             \
        const u16* base = (kg < K1) ? (A + kg) : (A2 + (kg - K1));            \
        ra0 = *(const uint4*)(base + (size_t)(m0 + ar) * 512);                \
        ra1 = *(const uint4*)(base + (size_t)(m0 + ar + 64) * 512);           \
        if constexpr (ISBF) {                                                 \
            rbb = *(const uint4*)(Bb + (size_t)((k0) + bkr) * 512 + n0 + nb); \
        } else {                                                              \
            const float* Bp_ = Bf + (size_t)((k0) + bkr) * 512 + n0 + nb;     \
            rf0 = *(const float4*)(Bp_ + 0);                                  \
            rf1 = *(const float4*)(Bp_ + 4);                                  \
        }                                                                     \
    }

#define STORE(pp)                                                             \
    {                                                                         \
        *(uint4*)&As0[(pp) * 9216 + ar * 72 + ac] = ra0;                      \
        *(uint4*)&As0[(pp) * 9216 + (ar + 64) * 72 + ac] = ra1;               \
        u16 bvals[8];                                                         \
        if constexpr (ISBF) {                                                 \
            union { uint4 v; u16 s[8]; } ub; ub.v = rbb;                      \
            _Pragma("unroll")                                                 \
            for (int i = 0; i < 8; ++i) bvals[i] = ub.s[i];                   \
        } else {                                                              \
            bvals[0] = f2bfu(rf0.x); bvals[1] = f2bfu(rf0.y);                 \
            bvals[2] = f2bfu(rf0.z); bvals[3] = f2bfu(rf0.w);                 \
            bvals[4] = f2bfu(rf1.x); bvals[5] = f2bfu(rf1.y);                 \
            bvals[6] = f2bfu(rf1.z); bvals[7] = f2bfu(rf1.w);                 \
        }                                                                     \
        const int slot_ = (((bkr >> 3) + jn) & 7) * 8 + (bkr & 7);            \
        _Pragma("unroll")                                                     \
        for (int i = 0; i < 8; ++i)                                           \
            Bs0[(pp) * 4608 + (nb + i) * 72 + slot_] = bvals[i];              \
    }

template<bool ISBF>
__device__ __forceinline__ void gemm_tile(
    const u16* __restrict__ A, const u16* __restrict__ A2, const int K1,
    const void* __restrict__ Bv, const void* __restrict__ biasv,
    u16* __restrict__ C, const int K, const int m0, const int n0,
    u16* __restrict__ As0, u16* __restrict__ Bs0)
{
    const int tid  = threadIdx.x;          // 0..511
    const int lane = tid & 63;
    const int wid = tid >> 6;              // 0..7
    const int wm  = (wid & 3) * 32;
    const int wn  = (wid >> 2) * 32;
    const int ar  = tid >> 3;              // 0..63 (A rows; also +64)
    const int ac  = (tid & 7) * 8;         // k-col within BK=64
    const int bkr = tid >> 3;              // 0..63 B k-row
    const int jn  = tid & 7;
    const int nb  = jn * 8;
    const int lm = lane & 15;
    const int kq = lane >> 4;

    const u16*   Bb = (const u16*)Bv;
    const float* Bf = (const float*)Bv;

    f32x4 acc[2][2];
    #pragma unroll
    for (int i = 0; i < 2; ++i)
        #pragma unroll
        for (int j = 0; j < 2; ++j)
            acc[i][j] = (f32x4){0.f, 0.f, 0.f, 0.f};

    GEMM_FETCH_STORE_BK64
    GEMM_KLOOP_BK64

    // epilogue: bias + tanh + bf16 store (identical to r10/r16)
    #pragma unroll
    for (int j = 0; j < 2; ++j) {
        const int n = n0 + wn + j * 16 + lm;
        const float bsv = ISBF ? bfu2f(((const u16*)biasv)[n])
                               : ((const float*)biasv)[n];
        #pragma unroll
        for (int i = 0; i < 2; ++i) {
            #pragma unroll
            for (int r = 0; r < 4; ++r) {
                const int m = m0 + wm + i * 16 + kq * 4 + r;
                C[(size_t)m * 512 + n] = f2bfu(fast_tanh(acc[i][j][r] + bsv));
            }
        }
    }
}

__global__ __launch_bounds__(512, 4) void gemm_mfma(
    const u16* __restrict__ A, const u16* __restrict__ A2, int K1,
    const void* __restrict__ B, const void* __restrict__ bias,
    u16* __restrict__ C, int K,
    const u16* __restrict__ Wdet, const unsigned int* __restrict__ Mdet)
{
    __shared__ __align__(16) u16 As[2 * 128 * 72];   // 36.9 KB
    __shared__ __align__(16) u16 Bs[2 * 64 * 72];    // 18.4 KB
    __shared__ int s_flags;

    if (threadIdx.x < 64) {
        int fl = detect_wave(Wdet, Mdet, threadIdx.x);
        if (threadIdx.x == 0) s_flags = fl;
    }
    __syncthreads();
    const int m0 = blockIdx.x * 128;
    const int n0 = blockIdx.y * 64;
    if (s_flags & 1) gemm_tile<true >(A, A2, K1, B, bias, C, K, m0, n0, As, Bs);
    else             gemm_tile<false>(A, A2, K1, B, bias, C, K, m0, n0, As, Bs);
}

// ---------------------------------------------------------------------------
// Kernel 3: GEMM3 + logits (same BK=64 loop; r14 logits epilogue, passed
// twice). H kept in regs; logits via shfl-reduce + f32 atomicAdd.
// ---------------------------------------------------------------------------
template<bool ISBF>
__device__ __forceinline__ void g3_body(
    const u16* __restrict__ A, const u16* __restrict__ A2, const int K1,
    const void* __restrict__ Bv, const void* __restrict__ biasv,
    const void* __restrict__ w2v, const void* __restrict__ cb2v,
    float* __restrict__ outp, const int K,
    u16* __restrict__ As0, u16* __restrict__ Bs0)
{
    const int tid  = threadIdx.x;
    const int lane = tid & 63;
    const int wid = tid >> 6;
    const int wm  = (wid & 3) * 32;
    const int wn  = (wid >> 2) * 32;
    const int ar  = tid >> 3;
    const int ac  = (tid & 7) * 8;
    const int bkr = tid >> 3;
    const int jn  = tid & 7;
    const int nb  = jn * 8;
    const int lm = lane & 15;
    const int kq = lane >> 4;
    const int m0 = (blockIdx.x & 31) * 128;
    const int n0 = (blockIdx.x >> 5) * 64;

    const u16*   Bb = (const u16*)Bv;
    const float* Bf = (const float*)Bv;

    f32x4 acc[2][2];
    #pragma unroll
    for (int i = 0; i < 2; ++i)
        #pragma unroll
        for (int j = 0; j < 2; ++j)
            acc[i][j] = (f32x4){0.f, 0.f, 0.f, 0.f};

    GEMM_FETCH_STORE_BK64
    GEMM_KLOOP_BK64

    // epilogue: H = tanh(acc + cb1[n]); logits partials; lm-reduce; atomics
    float lg[2][4][3];
    #pragma unroll
    for (int i = 0; i < 2; ++i)
        #pragma unroll
        for (int r = 0; r < 4; ++r)
            #pragma unroll
            for (int l = 0; l < 3; ++l) lg[i][r][l] = 0.f;

    #pragma unroll
    for (int j = 0; j < 2; ++j) {
        const int n = n0 + wn + j * 16 + lm;
        const float bsv = ISBF ? bfu2f(((const u16*)biasv)[n])
                               : ((const float*)biasv)[n];
        float wc[3];
        #pragma unroll
        for (int l = 0; l < 3; ++l)
            wc[l] = ISBF ? bfu2f(((const u16*)w2v)[n * 3 + l])
                         : ((const float*)w2v)[n * 3 + l];
        #pragma unroll
        for (int i = 0; i < 2; ++i)
            #pragma unroll
            for (int r = 0; r < 4; ++r) {
                const float h = fast_tanh(acc[i][j][r] + bsv);
                #pragma unroll
                for (int l = 0; l < 3; ++l) lg[i][r][l] += h * wc[l];
            }
    }
    #pragma unroll
    for (int off = 1; off <= 8; off <<= 1)
        #pragma unroll
        for (int i = 0; i < 2; ++i)
            #pragma unroll
            for (int r = 0; r < 4; ++r)
                #pragma unroll
                for (int l = 0; l < 3; ++l)
                    lg[i][r][l] += __shfl_xor(lg[i][r][l], off);

    if (lm == 0) {
        const bool addb = (n0 == 0) && (wn == 0);   // exactly one per (m,l)
        float cb[3];
        #pragma unroll
        for (int l = 0; l < 3; ++l)
            cb[l] = ISBF ? bfu2f(((const u16*)cb2v)[l])
                         : ((const float*)cb2v)[l];
        #pragma unroll
        for (int i = 0; i < 2; ++i)
            #pragma unroll
            for (int r = 0; r < 4; ++r) {
                const int m = m0 + wm + i * 16 + kq * 4 + r;
                #pragma unroll
                for (int l = 0; l < 3; ++l) {
                    float v = lg[i][r][l];
                    if (addb) v += cb[l];
                    atomicAdd(&outp[m * 3 + l], v);
                }
            }
    }
}

__global__ __launch_bounds__(512, 4) void gemm3_logits(
    const u16* __restrict__ A, const u16* __restrict__ A2, int K1,
    const void* __restrict__ B, const void* __restrict__ bias,
    const void* __restrict__ w2, const void* __restrict__ cb2,
    float* __restrict__ out, int K,
    const u16* __restrict__ Wdet, const unsigned int* __restrict__ Mdet)
{
    __shared__ __align__(16) u16 As[2 * 128 * 72];
    __shared__ __align__(16) u16 Bs[2 * 64 * 72];
    __shared__ int s_flags;

    if (threadIdx.x < 64) {
        int fl = detect_wave(Wdet, Mdet, threadIdx.x);
        if (threadIdx.x == 0) s_flags = fl;
    }
    __syncthreads();
    if (s_flags & 1)
        g3_body<true >(A, A2, K1, B, bias, w2, cb2, out, K, As, Bs);
    else
        g3_body<false>(A, A2, K1, B, bias, w2, cb2, out, K, As, Bs);
}

// ---------------------------------------------------------------------------
extern "C" void kernel_launch(void* const* d_in, const int* in_sizes, int n_in,
                              void* d_out, int out_size, void* d_ws, size_t ws_size,
                              hipStream_t stream)
{
    const int* ids_a  = (const int*)d_in[0];
    const int* ids_b  = (const int*)d_in[1];
    const void* mask_a = d_in[2];
    const void* mask_b = d_in[3];
    const void* W_emb  = d_in[4];
    const void* enc_w1 = d_in[5];
    const void* enc_b1 = d_in[6];
    const void* enc_w2 = d_in[7];
    const void* enc_b2 = d_in[8];
    const void* cls_w1 = d_in[9];
    const void* cls_b1 = d_in[10];
    const void* cls_w2 = d_in[11];
    const void* cls_b2 = d_in[12];

    const u16* Wdet = (const u16*)W_emb;
    const unsigned int* Mdet = (const unsigned int*)mask_a;

    u16* buf0 = (u16*)d_ws;                          // 8192*512 bf16 = 8 MB
    u16* buf1 = buf0 + (size_t)8192 * 512;           // 8 MB
    float* outp = (float*)d_out;

    // P -> buf0 (rows 0..4095 side a, 4096..8191 side b); also zeroes d_out
    pool_kernel<<<8192, 128, 0, stream>>>(ids_a, ids_b, mask_a, mask_b,
                                          W_emb, buf0, outp, Mdet);

    // X1 = tanh(P @ w1 + b1) -> buf1
    gemm_mfma<<<dim3(64, 8), 512, 0, stream>>>(
        buf0, buf0, 512, enc_w1, enc_b1, buf1, 512, Wdet, Mdet);

    // X2 = tanh(X1 @ w2 + b2) -> buf0
    gemm_mfma<<<dim3(64, 8), 512, 0, stream>>>(
        buf1, buf1, 512, enc_w2, enc_b2, buf0, 512, Wdet, Mdet);

    // logits = tanh([va|vb]@cw1+cb1) @ cw2 + cb2 -> d_out (f32, atomics)
    gemm3_logits<<<256, 512, 0, stream>>>(
        buf0, buf0 + (size_t)4096 * 512, 512, cls_w1, cls_b1,
        cls_w2, cls_b2, outp, 1024, Wdet, Mdet);
}

// Round 10
// 333.637 us; speedup vs baseline: 1.2930x; 1.0612x over previous
//
#include <hip/hip_runtime.h>

// SemNN — twin-tower masked-pool encoder + classifier.
// B=4096, S=128, D=512, VOCAB=50000, NUM_LABELS=3.
// Confirmed: float inputs bf16 (detector keeps f32 fallback), ids int32,
// masks int-like, OUTPUT f32. ws usage: 16 MB.
//
// Round 18:
//  * ACCOUNTING CLOSED: r11/r13 in-kernel timestamps vs wall shows a fixed
//    ~150us per-iteration harness overhead outside all kernels (840 = 164
//    pool + 516 fused + 160; 1039 = 163 + 725 + 151). With that, the GEMM
//    stack is ~40-50us (matches bottom-up model); six rounds of "slow
//    GEMMs" were an accounting artifact. Remaining lever: pool (162us).
//  * POOL v2 (column-sliced for L2 residency): the 51.2MB table can't fit
//    a 4MB per-XCD L2 -> 508MB of 1KB random gathers all miss L2 (3.3TB/s
//    fabric floor). A 64-col slice = 6.4MB ~fits. Block bid: row=bid>>3,
//    slice=bid&7; with round-robin bid%8 -> XCD mapping, slice s gathers
//    from a 6.4MB footprint resident in XCD s's L2. Lane owns 1 col (2B
//    loads, 128B/wave), 8-deep MLP, no LDS combine (1 wave/block).
//    Predicted: FETCH 508->~300MB, pool 162->~100us.
//    Falsifier: FETCH unchanged => %8 mapping wrong => revert next round.
//  * GEMMs byte-identical to r17 (354us best): BK=64, 8 waves, dbuf LDS,
//    g3 carries fused logits epilogue (atomicAdd into zeroed d_out).
//  * d_out zeroing folded into pool (slice-7 blocks of rows 0..95).

typedef unsigned short u16;
typedef __attribute__((ext_vector_type(8))) short short8;
typedef __attribute__((ext_vector_type(4))) float f32x4;

__device__ __forceinline__ float bfu2f(u16 u) {
    union { unsigned int i; float f; } v;
    v.i = ((unsigned int)u) << 16;
    return v.f;
}

__device__ __forceinline__ u16 f2bfu(float f) {
    union { float f; unsigned int i; } v;
    v.f = f;
    unsigned int x = v.i;
    x += 0x7fffu + ((x >> 16) & 1u);   // RNE
    return (u16)(x >> 16);
}

// tanh(x) = (e^{2x}-1)/(e^{2x}+1) using hw exp2; |x| clamped so e stays
// finite. ~1e-7 rel error, plenty for bf16-rounded outputs.
__device__ __forceinline__ float fast_tanh(float x) {
    float xc = fminf(fmaxf(x, -15.f), 15.f);
    float e = __builtin_amdgcn_exp2f(xc * 2.885390082f);  // 2*log2(e)*x
    return (e - 1.f) / (e + 1.f);
}

// Wave-collective dtype detection; every lane returns flags:
//   bit0: float tensors are bf16 (vs f32); bits2-3: mask type
//   0=int32, 1=byte-bool, 2=bf16, 3=f32
__device__ __forceinline__ int detect_wave(const u16* __restrict__ W,
                                           const unsigned int* __restrict__ m,
                                           int lane)
{
    int cnt = 0;
    int w01 = 1, b01 = 1, lo16 = 0;
    #pragma unroll
    for (int j = lane; j < 256; j += 64) {
        u16 u = W[1024 + 2 * j];
        int e = (u >> 7) & 0xFF;
        cnt += (e >= 0x6A && e <= 0x7E) ? 1 : 0;
        unsigned int v = m[j];
        w01 &= (v <= 1u) ? 1 : 0;
        b01 &= ((v & ~0x01010101u) == 0u) ? 1 : 0;
        lo16 |= ((v & 0xFFFFu) == 0x3F80u) ? 1 : 0;
    }
    #pragma unroll
    for (int off = 32; off > 0; off >>= 1) {
        cnt  += __shfl_down(cnt, off);
        w01  &= __shfl_down(w01, off);
        b01  &= __shfl_down(b01, off);
        lo16 |= __shfl_down(lo16, off);
    }
    int mtype;
    if (w01)        mtype = 0;
    else if (b01)   mtype = 1;
    else if (lo16)  mtype = 2;
    else            mtype = 3;
    int fl = ((cnt >= 128) ? 1 : 0) | (mtype << 2);
    return __shfl(fl, 0);
}

__device__ __forceinline__ int mask_nonzero(const void* __restrict__ msk,
                                            int idx, int mtype)
{
    switch (mtype) {
        case 0:  return ((const int*)msk)[idx] != 0;
        case 1:  return ((const unsigned char*)msk)[idx] != 0;
        case 2:  return ((const u16*)msk)[idx] != 0;
        default: return ((const unsigned int*)msk)[idx] != 0u;
    }
}

// ---------------------------------------------------------------------------
// Kernel 1: column-sliced embedding gather + masked sum-pool -> P [8192,512].
// 65536 blocks x 64 threads. bid: row = bid>>3 (0..8191; >=4096 = side b),
// slice = bid&7 (64 cols). With round-robin bid%8->XCD, slice s's 6.4MB
// table-column footprint stays L2-resident on one XCD.
// Lane owns column slice*64+t; per token one u16 (128B/wave, coalesced).
// ---------------------------------------------------------------------------
__global__ __launch_bounds__(64) void pool_kernel(
    const int* __restrict__ ids_a, const int* __restrict__ ids_b,
    const void* __restrict__ mska, const void* __restrict__ mskb,
    const void* __restrict__ W, u16* __restrict__ P,
    float* __restrict__ outz,
    const unsigned int* __restrict__ Mdet)
{
    __shared__ int s_ids[132];
    __shared__ int s_cnt;
    const int t     = threadIdx.x;         // 0..63
    const int bid   = blockIdx.x;          // 0..65535
    const int slice = bid & 7;
    const int row   = bid >> 3;            // 0..8191
    const int r     = row & 4095;

    // fold d_out zeroing into this dispatch: slice-7 blocks of rows 0..95
    // (96 blocks x 64 thr x 2 = 12288 = 4096*3 floats)
    if (slice == 7 && row < 96) {
        outz[row * 128 + t]      = 0.f;
        outz[row * 128 + 64 + t] = 0.f;
    }

    if (t == 0) s_cnt = 0;
    const int fl = detect_wave((const u16*)W, Mdet, t);
    const bool isbf  = (fl & 1) != 0;
    const int  mtype = (fl >> 2) & 3;

    const int* __restrict__ ids = (row < 4096) ? ids_a : ids_b;
    const void* __restrict__ msk = (row < 4096) ? mska : mskb;

    __syncthreads();
    // compaction: thread t handles tokens t and t+64
    {
        const int id0 = ids[r * 128 + t];
        const int id1 = ids[r * 128 + 64 + t];
        if (mask_nonzero(msk, r * 128 + t, mtype))
            s_ids[atomicAdd(&s_cnt, 1)] = id0;
        if (mask_nonzero(msk, r * 128 + 64 + t, mtype))
            s_ids[atomicAdd(&s_cnt, 1)] = id1;
    }
    __syncthreads();
    const int cnt = s_cnt;

    const int col = slice * 64 + t;
    float acc = 0.f;
    if (isbf) {
        const u16* __restrict__ Wb = (const u16*)W + col;
        int j = 0;
        for (; j + 7 < cnt; j += 8) {      // 8 loads in flight
            const u16 v0 = Wb[(size_t)s_ids[j + 0] * 512];
            const u16 v1 = Wb[(size_t)s_ids[j + 1] * 512];
            const u16 v2 = Wb[(size_t)s_ids[j + 2] * 512];
            const u16 v3 = Wb[(size_t)s_ids[j + 3] * 512];
            const u16 v4 = Wb[(size_t)s_ids[j + 4] * 512];
            const u16 v5 = Wb[(size_t)s_ids[j + 5] * 512];
            const u16 v6 = Wb[(size_t)s_ids[j + 6] * 512];
            const u16 v7 = Wb[(size_t)s_ids[j + 7] * 512];
            acc += ((bfu2f(v0) + bfu2f(v1)) + (bfu2f(v2) + bfu2f(v3))) +
                   ((bfu2f(v4) + bfu2f(v5)) + (bfu2f(v6) + bfu2f(v7)));
        }
        for (; j < cnt; ++j)
            acc += bfu2f(Wb[(size_t)s_ids[j] * 512]);
    } else {
        const float* __restrict__ Wf = (const float*)W + col;
        int j = 0;
        for (; j + 3 < cnt; j += 4) {
            const float v0 = Wf[(size_t)s_ids[j + 0] * 512];
            const float v1 = Wf[(size_t)s_ids[j + 1] * 512];
            const float v2 = Wf[(size_t)s_ids[j + 2] * 512];
            const float v3 = Wf[(size_t)s_ids[j + 3] * 512];
            acc += (v0 + v1) + (v2 + v3);
        }
        for (; j < cnt; ++j)
            acc += Wf[(size_t)s_ids[j] * 512];
    }
    P[(size_t)row * 512 + col] = f2bfu(acc);
}

// ---------------------------------------------------------------------------
// GEMM tile, BK=64 (r17, measured best): C[m0:+128, n0:+64] over K (N=512).
// 512 thr, 8 waves 4m x 2n (wave 32x32, acc 2x2). A LDS [128][72] u16;
// B LDS [64][72] 8-chunk rotate swizzle. Double-buffered, 1 barrier/step.
// ---------------------------------------------------------------------------
#define GEMM_KLOOP_BK64                                                        \
    FETCH(0)                                                                   \
    STORE(0)                                                                   \
    FETCH(64)                                                                  \
    __syncthreads();                                                           \
    int p = 0;                                                                 \
    for (int k0 = 0; k0 < K; k0 += 64) {                                       \
        if (k0 + 64 < K) {                                                     \
            STORE(p ^ 1)                                                       \
            if (k0 + 128 < K) FETCH(k0 + 128)                                  \
        }                                                                      \
        const u16* Ap  = As0 + p * 9216;                                       \
        const u16* Bp2 = Bs0 + p * 4608;                                       \
        short8 af0[2], af1[2], bf0[2], bf1[2];                                 \
        _Pragma("unroll")                                                      \
        for (int i = 0; i < 2; ++i) {                                          \
            af0[i] = *(const short8*)&Ap[(wm + i * 16 + lm) * 72 + kq * 8];    \
            af1[i] = *(const short8*)&Ap[(wm + i * 16 + lm) * 72 + 32 + kq * 8];\
        }                                                                      \
        _Pragma("unroll")                                                      \
        for (int j = 0; j < 2; ++j) {                                          \
            const int n = wn + j * 16 + lm;                                    \
            bf0[j] = *(const short8*)&Bp2[n * 72 + ((kq + (n >> 3)) & 7) * 8]; \
            bf1[j] = *(const short8*)&Bp2[n * 72 + ((4 + kq + (n >> 3)) & 7) * 8];\
        }                                                                      \
        _Pragma("unroll")                                                      \
        for (int i = 0; i < 2; ++i)                                            \
            _Pragma("unroll")                                                  \
            for (int j = 0; j < 2; ++j) {                                      \
                acc[i][j] = __builtin_amdgcn_mfma_f32_16x16x32_bf16(           \
                    af0[i], bf0[j], acc[i][j], 0, 0, 0);                       \
                acc[i][j] = __builtin_amdgcn_mfma_f32_16x16x32_bf16(           \
                    af1[i], bf1[j], acc[i][j], 0, 0, 0);                       \
            }                                                                  \
        if (k0 + 64 < K) __syncthreads();                                      \
        p ^= 1;                                                                \
    }

#define GEMM_FETCH_STORE_BK64                                                  \
    uint4 ra0, ra1, rbb;                                                       \
    float4 rf0, rf1;                                                           \
    (void)rf0; (void)rf1;

#define FETCH(k0)                                                             \
    {                                                                         \
        const int kg = (k0) + ac;                                             \
        const u16* base = (kg < K1) ? (A + kg) : (A2 + (kg - K1));            \
        ra0 = *(const uint4*)(base + (size_t)(m0 + ar) * 512);                \
        ra1 = *(const uint4*)(base + (size_t)(m0 + ar + 64) * 512);           \
        if constexpr (ISBF) {                                                 \
            rbb = *(const uint4*)(Bb + (size_t)((k0) + bkr) * 512 + n0 + nb); \
        } else {                                                              \
            const float* Bp_ = Bf + (size_t)((k0) + bkr) * 512 + n0 + nb;     \
            rf0 = *(const float4*)(Bp_ + 0);                                  \
            rf1 = *(const float4*)(Bp_ + 4);                                  \
        }                                                                     \
    }

#define STORE(pp)                                                             \
    {                                                                         \
        *(uint4*)&As0[(pp) * 9216 + ar * 72 + ac] = ra0;                      \
        *(uint4*)&As0[(pp) * 9216 + (ar + 64) * 72 + ac] = ra1;               \
        u16 bvals[8];                                                         \
        if constexpr (ISBF) {                                                 \
            union { uint4 v; u16 s[8]; } ub; ub.v = rbb;                      \
            _Pragma("unroll")                                                 \
            for (int i = 0; i < 8; ++i) bvals[i] = ub.s[i];                   \
        } else {                                                              \
            bvals[0] = f2bfu(rf0.x); bvals[1] = f2bfu(rf0.y);                 \
            bvals[2] = f2bfu(rf0.z); bvals[3] = f2bfu(rf0.w);                 \
            bvals[4] = f2bfu(rf1.x); bvals[5] = f2bfu(rf1.y);                 \
            bvals[6] = f2bfu(rf1.z); bvals[7] = f2bfu(rf1.w);                 \
        }                                                                     \
        const int slot_ = (((bkr >> 3) + jn) & 7) * 8 + (bkr & 7);            \
        _Pragma("unroll")                                                     \
        for (int i = 0; i < 8; ++i)                                           \
            Bs0[(pp) * 4608 + (nb + i) * 72 + slot_] = bvals[i];              \
    }

template<bool ISBF>
__device__ __forceinline__ void gemm_tile(
    const u16* __restrict__ A, const u16* __restrict__ A2, const int K1,
    const void* __restrict__ Bv, const void* __restrict__ biasv,
    u16* __restrict__ C, const int K, const int m0, const int n0,
    u16* __restrict__ As0, u16* __restrict__ Bs0)
{
    const int tid  = threadIdx.x;          // 0..511
    const int lane = tid & 63;
    const int wid = tid >> 6;              // 0..7
    const int wm  = (wid & 3) * 32;
    const int wn  = (wid >> 2) * 32;
    const int ar  = tid >> 3;              // 0..63 (A rows; also +64)
    const int ac  = (tid & 7) * 8;         // k-col within BK=64
    const int bkr = tid >> 3;              // 0..63 B k-row
    const int jn  = tid & 7;
    const int nb  = jn * 8;
    const int lm = lane & 15;
    const int kq = lane >> 4;

    const u16*   Bb = (const u16*)Bv;
    const float* Bf = (const float*)Bv;

    f32x4 acc[2][2];
    #pragma unroll
    for (int i = 0; i < 2; ++i)
        #pragma unroll
        for (int j = 0; j < 2; ++j)
            acc[i][j] = (f32x4){0.f, 0.f, 0.f, 0.f};

    GEMM_FETCH_STORE_BK64
    GEMM_KLOOP_BK64

    // epilogue: bias + tanh + bf16 store
    #pragma unroll
    for (int j = 0; j < 2; ++j) {
        const int n = n0 + wn + j * 16 + lm;
        const float bsv = ISBF ? bfu2f(((const u16*)biasv)[n])
                               : ((const float*)biasv)[n];
        #pragma unroll
        for (int i = 0; i < 2; ++i) {
            #pragma unroll
            for (int r = 0; r < 4; ++r) {
                const int m = m0 + wm + i * 16 + kq * 4 + r;
                C[(size_t)m * 512 + n] = f2bfu(fast_tanh(acc[i][j][r] + bsv));
            }
        }
    }
}

__global__ __launch_bounds__(512, 4) void gemm_mfma(
    const u16* __restrict__ A, const u16* __restrict__ A2, int K1,
    const void* __restrict__ B, const void* __restrict__ bias,
    u16* __restrict__ C, int K,
    const u16* __restrict__ Wdet, const unsigned int* __restrict__ Mdet)
{
    __shared__ __align__(16) u16 As[2 * 128 * 72];   // 36.9 KB
    __shared__ __align__(16) u16 Bs[2 * 64 * 72];    // 18.4 KB
    __shared__ int s_flags;

    if (threadIdx.x < 64) {
        int fl = detect_wave(Wdet, Mdet, threadIdx.x);
        if (threadIdx.x == 0) s_flags = fl;
    }
    __syncthreads();
    const int m0 = blockIdx.x * 128;
    const int n0 = blockIdx.y * 64;
    if (s_flags & 1) gemm_tile<true >(A, A2, K1, B, bias, C, K, m0, n0, As, Bs);
    else             gemm_tile<false>(A, A2, K1, B, bias, C, K, m0, n0, As, Bs);
}

// ---------------------------------------------------------------------------
// Kernel 3: GEMM3 + logits (r17). H kept in regs; logits via shfl-reduce
// over lm lanes + f32 atomicAdd into zeroed d_out.
// ---------------------------------------------------------------------------
template<bool ISBF>
__device__ __forceinline__ void g3_body(
    const u16* __restrict__ A, const u16* __restrict__ A2, const int K1,
    const void* __restrict__ Bv, const void* __restrict__ biasv,
    const void* __restrict__ w2v, const void* __restrict__ cb2v,
    float* __restrict__ outp, const int K,
    u16* __restrict__ As0, u16* __restrict__ Bs0)
{
    const int tid  = threadIdx.x;
    const int lane = tid & 63;
    const int wid = tid >> 6;
    const int wm  = (wid & 3) * 32;
    const int wn  = (wid >> 2) * 32;
    const int ar  = tid >> 3;
    const int ac  = (tid & 7) * 8;
    const int bkr = tid >> 3;
    const int jn  = tid & 7;
    const int nb  = jn * 8;
    const int lm = lane & 15;
    const int kq = lane >> 4;
    const int m0 = (blockIdx.x & 31) * 128;
    const int n0 = (blockIdx.x >> 5) * 64;

    const u16*   Bb = (const u16*)Bv;
    const float* Bf = (const float*)Bv;

    f32x4 acc[2][2];
    #pragma unroll
    for (int i = 0; i < 2; ++i)
        #pragma unroll
        for (int j = 0; j < 2; ++j)
            acc[i][j] = (f32x4){0.f, 0.f, 0.f, 0.f};

    GEMM_FETCH_STORE_BK64
    GEMM_KLOOP_BK64

    // epilogue: H = tanh(acc + cb1[n]); logits partials; lm-reduce; atomics
    float lg[2][4][3];
    #pragma unroll
    for (int i = 0; i < 2; ++i)
        #pragma unroll
        for (int r = 0; r < 4; ++r)
            #pragma unroll
            for (int l = 0; l < 3; ++l) lg[i][r][l] = 0.f;

    #pragma unroll
    for (int j = 0; j < 2; ++j) {
        const int n = n0 + wn + j * 16 + lm;
        const float bsv = ISBF ? bfu2f(((const u16*)biasv)[n])
                               : ((const float*)biasv)[n];
        float wc[3];
        #pragma unroll
        for (int l = 0; l < 3; ++l)
            wc[l] = ISBF ? bfu2f(((const u16*)w2v)[n * 3 + l])
                         : ((const float*)w2v)[n * 3 + l];
        #pragma unroll
        for (int i = 0; i < 2; ++i)
            #pragma unroll
            for (int r = 0; r < 4; ++r) {
                const float h = fast_tanh(acc[i][j][r] + bsv);
                #pragma unroll
                for (int l = 0; l < 3; ++l) lg[i][r][l] += h * wc[l];
            }
    }
    #pragma unroll
    for (int off = 1; off <= 8; off <<= 1)
        #pragma unroll
        for (int i = 0; i < 2; ++i)
            #pragma unroll
            for (int r = 0; r < 4; ++r)
                #pragma unroll
                for (int l = 0; l < 3; ++l)
                    lg[i][r][l] += __shfl_xor(lg[i][r][l], off);

    if (lm == 0) {
        const bool addb = (n0 == 0) && (wn == 0);   // exactly one per (m,l)
        float cb[3];
        #pragma unroll
        for (int l = 0; l < 3; ++l)
            cb[l] = ISBF ? bfu2f(((const u16*)cb2v)[l])
                         : ((const float*)cb2v)[l];
        #pragma unroll
        for (int i = 0; i < 2; ++i)
            #pragma unroll
            for (int r = 0; r < 4; ++r) {
                const int m = m0 + wm + i * 16 + kq * 4 + r;
                #pragma unroll
                for (int l = 0; l < 3; ++l) {
                    float v = lg[i][r][l];
                    if (addb) v += cb[l];
                    atomicAdd(&outp[m * 3 + l], v);
                }
            }
    }
}

__global__ __launch_bounds__(512, 4) void gemm3_logits(
    const u16* __restrict__ A, const u16* __restrict__ A2, int K1,
    const void* __restrict__ B, const void* __restrict__ bias,
    const void* __restrict__ w2, const void* __restrict__ cb2,
    float* __restrict__ out, int K,
    const u16* __restrict__ Wdet, const unsigned int* __restrict__ Mdet)
{
    __shared__ __align__(16) u16 As[2 * 128 * 72];
    __shared__ __align__(16) u16 Bs[2 * 64 * 72];
    __shared__ int s_flags;

    if (threadIdx.x < 64) {
        int fl = detect_wave(Wdet, Mdet, threadIdx.x);
        if (threadIdx.x == 0) s_flags = fl;
    }
    __syncthreads();
    if (s_flags & 1)
        g3_body<true >(A, A2, K1, B, bias, w2, cb2, out, K, As, Bs);
    else
        g3_body<false>(A, A2, K1, B, bias, w2, cb2, out, K, As, Bs);
}

// ---------------------------------------------------------------------------
extern "C" void kernel_launch(void* const* d_in, const int* in_sizes, int n_in,
                              void* d_out, int out_size, void* d_ws, size_t ws_size,
                              hipStream_t stream)
{
    const int* ids_a  = (const int*)d_in[0];
    const int* ids_b  = (const int*)d_in[1];
    const void* mask_a = d_in[2];
    const void* mask_b = d_in[3];
    const void* W_emb  = d_in[4];
    const void* enc_w1 = d_in[5];
    const void* enc_b1 = d_in[6];
    const void* enc_w2 = d_in[7];
    const void* enc_b2 = d_in[8];
    const void* cls_w1 = d_in[9];
    const void* cls_b1 = d_in[10];
    const void* cls_w2 = d_in[11];
    const void* cls_b2 = d_in[12];

    const u16* Wdet = (const u16*)W_emb;
    const unsigned int* Mdet = (const unsigned int*)mask_a;

    u16* buf0 = (u16*)d_ws;                          // 8192*512 bf16 = 8 MB
    u16* buf1 = buf0 + (size_t)8192 * 512;           // 8 MB
    float* outp = (float*)d_out;

    // P -> buf0 (rows 0..4095 side a, 4096..8191 side b); also zeroes d_out.
    // 65536 blocks: row = bid>>3, col-slice = bid&7 (XCD-resident table slice)
    pool_kernel<<<65536, 64, 0, stream>>>(ids_a, ids_b, mask_a, mask_b,
                                          W_emb, buf0, outp, Mdet);

    // X1 = tanh(P @ w1 + b1) -> buf1
    gemm_mfma<<<dim3(64, 8), 512, 0, stream>>>(
        buf0, buf0, 512, enc_w1, enc_b1, buf1, 512, Wdet, Mdet);

    // X2 = tanh(X1 @ w2 + b2) -> buf0
    gemm_mfma<<<dim3(64, 8), 512, 0, stream>>>(
        buf1, buf1, 512, enc_w2, enc_b2, buf0, 512, Wdet, Mdet);

    // logits = tanh([va|vb]@cw1+cb1) @ cw2 + cb2 -> d_out (f32, atomics)
    gemm3_logits<<<256, 512, 0, stream>>>(
        buf0, buf0 + (size_t)4096 * 512, 512, cls_w1, cls_b1,
        cls_w2, cls_b2, outp, 1024, Wdet, Mdet);
}

// Round 12
// 332.252 us; speedup vs baseline: 1.2984x; 1.0042x over previous
//
#include <hip/hip_runtime.h>

// SemNN — twin-tower masked-pool encoder + classifier.
// B=4096, S=128, D=512, VOCAB=50000, NUM_LABELS=3.
// Confirmed: float inputs bf16 (detector keeps f32 fallback), ids int32,
// masks int-like, OUTPUT f32. ws usage: 16 MB.
//
// Round 20 (= round 19 resubmitted; r19 died to infra "container failed
// twice" — audit found no hang/compile hazard: branch-free wave-uniform
// ballots, bijective compaction, no spins/fences, GEMMs byte-identical to
// twice-passed r17/r18):
//  * POOL v3:
//    (a) ballot compaction — block is 1 wave; __ballot/__popcll prefix
//        replaces the 128 serialized LDS atomicAdds (r18 VALUBusy=35%).
//    (b) vocab-range phasing — tokens compacted low-vocab (<25600) first,
//        then high; co-paced blocks keep each XCD's temporal footprint
//        ~3.2MB (<4MB L2) per phase. Order-only change.
//  * GEMMs byte-identical to r17/r18 (BK=64, 8 waves, dbuf LDS; g3 carries
//    fused logits epilogue; d_out zeroing folded into pool slice-7 blocks).
//  * Falsifiers: FETCH stays ~400MB => phasing refuted. Container dies
//    again => this pool code kills the container; bisect next round.

typedef unsigned short u16;
typedef __attribute__((ext_vector_type(8))) short short8;
typedef __attribute__((ext_vector_type(4))) float f32x4;

__device__ __forceinline__ float bfu2f(u16 u) {
    union { unsigned int i; float f; } v;
    v.i = ((unsigned int)u) << 16;
    return v.f;
}

__device__ __forceinline__ u16 f2bfu(float f) {
    union { float f; unsigned int i; } v;
    v.f = f;
    unsigned int x = v.i;
    x += 0x7fffu + ((x >> 16) & 1u);   // RNE
    return (u16)(x >> 16);
}

// tanh(x) = (e^{2x}-1)/(e^{2x}+1) using hw exp2; |x| clamped so e stays
// finite. ~1e-7 rel error, plenty for bf16-rounded outputs.
__device__ __forceinline__ float fast_tanh(float x) {
    float xc = fminf(fmaxf(x, -15.f), 15.f);
    float e = __builtin_amdgcn_exp2f(xc * 2.885390082f);  // 2*log2(e)*x
    return (e - 1.f) / (e + 1.f);
}

// Wave-collective dtype detection; every lane returns flags:
//   bit0: float tensors are bf16 (vs f32); bits2-3: mask type
//   0=int32, 1=byte-bool, 2=bf16, 3=f32
__device__ __forceinline__ int detect_wave(const u16* __restrict__ W,
                                           const unsigned int* __restrict__ m,
                                           int lane)
{
    int cnt = 0;
    int w01 = 1, b01 = 1, lo16 = 0;
    #pragma unroll
    for (int j = lane; j < 256; j += 64) {
        u16 u = W[1024 + 2 * j];
        int e = (u >> 7) & 0xFF;
        cnt += (e >= 0x6A && e <= 0x7E) ? 1 : 0;
        unsigned int v = m[j];
        w01 &= (v <= 1u) ? 1 : 0;
        b01 &= ((v & ~0x01010101u) == 0u) ? 1 : 0;
        lo16 |= ((v & 0xFFFFu) == 0x3F80u) ? 1 : 0;
    }
    #pragma unroll
    for (int off = 32; off > 0; off >>= 1) {
        cnt  += __shfl_down(cnt, off);
        w01  &= __shfl_down(w01, off);
        b01  &= __shfl_down(b01, off);
        lo16 |= __shfl_down(lo16, off);
    }
    int mtype;
    if (w01)        mtype = 0;
    else if (b01)   mtype = 1;
    else if (lo16)  mtype = 2;
    else            mtype = 3;
    int fl = ((cnt >= 128) ? 1 : 0) | (mtype << 2);
    return __shfl(fl, 0);
}

__device__ __forceinline__ int mask_nonzero(const void* __restrict__ msk,
                                            int idx, int mtype)
{
    switch (mtype) {
        case 0:  return ((const int*)msk)[idx] != 0;
        case 1:  return ((const unsigned char*)msk)[idx] != 0;
        case 2:  return ((const u16*)msk)[idx] != 0;
        default: return ((const unsigned int*)msk)[idx] != 0u;
    }
}

// ---------------------------------------------------------------------------
// Kernel 1: column-sliced embedding gather + masked sum-pool -> P [8192,512].
// 65536 blocks x 64 threads (1 wave). bid: row = bid>>3, slice = bid&7;
// bid%8 -> XCD keeps each 64-col table slice on one XCD's L2.
// Ballot compaction (no atomics); tokens ordered low-vocab then high-vocab
// so the temporal footprint per XCD is ~3.2MB (<4MB L2) per phase.
// ---------------------------------------------------------------------------
__global__ __launch_bounds__(64) void pool_kernel(
    const int* __restrict__ ids_a, const int* __restrict__ ids_b,
    const void* __restrict__ mska, const void* __restrict__ mskb,
    const void* __restrict__ W, u16* __restrict__ P,
    float* __restrict__ outz,
    const unsigned int* __restrict__ Mdet)
{
    __shared__ int s_ids[128];
    const int t     = threadIdx.x;         // 0..63
    const int bid   = blockIdx.x;          // 0..65535
    const int slice = bid & 7;
    const int row   = bid >> 3;            // 0..8191
    const int r     = row & 4095;

    // fold d_out zeroing into this dispatch: slice-7 blocks of rows 0..95
    if (slice == 7 && row < 96) {
        outz[row * 128 + t]      = 0.f;
        outz[row * 128 + 64 + t] = 0.f;
    }

    const int fl = detect_wave((const u16*)W, Mdet, t);
    const bool isbf  = (fl & 1) != 0;
    const int  mtype = (fl >> 2) & 3;

    const int* __restrict__ ids = (row < 4096) ? ids_a : ids_b;
    const void* __restrict__ msk = (row < 4096) ? mska : mskb;

    // ballot compaction, low-vocab (<25600) first then high-vocab
    const int id0 = ids[r * 128 + t];
    const int id1 = ids[r * 128 + 64 + t];
    const int mk0 = mask_nonzero(msk, r * 128 + t, mtype);
    const int mk1 = mask_nonzero(msk, r * 128 + 64 + t, mtype);
    const unsigned long long below = (1ull << t) - 1ull;
    const unsigned long long bl0 = __ballot(mk0 && id0 <  25600);
    const unsigned long long bl1 = __ballot(mk1 && id1 <  25600);
    const unsigned long long bh0 = __ballot(mk0 && id0 >= 25600);
    const unsigned long long bh1 = __ballot(mk1 && id1 >= 25600);
    const int cl0  = __popcll(bl0);
    const int nlow = cl0 + __popcll(bl1);
    const int ch0  = __popcll(bh0);
    const int cnt  = nlow + ch0 + __popcll(bh1);
    if (mk0) {
        const int pos = (id0 < 25600)
                      ? __popcll(bl0 & below)
                      : nlow + __popcll(bh0 & below);
        s_ids[pos] = id0;
    }
    if (mk1) {
        const int pos = (id1 < 25600)
                      ? cl0 + __popcll(bl1 & below)
                      : nlow + ch0 + __popcll(bh1 & below);
        s_ids[pos] = id1;
    }
    __syncthreads();                       // 1 wave: just orders LDS w->r

    const int col = slice * 64 + t;
    float acc = 0.f;
    if (isbf) {
        const u16* __restrict__ Wb = (const u16*)W + col;
        int j = 0;
        for (; j + 7 < cnt; j += 8) {      // 8 loads in flight
            const u16 v0 = Wb[(size_t)s_ids[j + 0] * 512];
            const u16 v1 = Wb[(size_t)s_ids[j + 1] * 512];
            const u16 v2 = Wb[(size_t)s_ids[j + 2] * 512];
            const u16 v3 = Wb[(size_t)s_ids[j + 3] * 512];
            const u16 v4 = Wb[(size_t)s_ids[j + 4] * 512];
            const u16 v5 = Wb[(size_t)s_ids[j + 5] * 512];
            const u16 v6 = Wb[(size_t)s_ids[j + 6] * 512];
            const u16 v7 = Wb[(size_t)s_ids[j + 7] * 512];
            acc += ((bfu2f(v0) + bfu2f(v1)) + (bfu2f(v2) + bfu2f(v3))) +
                   ((bfu2f(v4) + bfu2f(v5)) + (bfu2f(v6) + bfu2f(v7)));
        }
        for (; j < cnt; ++j)
            acc += bfu2f(Wb[(size_t)s_ids[j] * 512]);
    } else {
        const float* __restrict__ Wf = (const float*)W + col;
        int j = 0;
        for (; j + 3 < cnt; j += 4) {
            const float v0 = Wf[(size_t)s_ids[j + 0] * 512];
            const float v1 = Wf[(size_t)s_ids[j + 1] * 512];
            const float v2 = Wf[(size_t)s_ids[j + 2] * 512];
            const float v3 = Wf[(size_t)s_ids[j + 3] * 512];
            acc += (v0 + v1) + (v2 + v3);
        }
        for (; j < cnt; ++j)
            acc += Wf[(size_t)s_ids[j] * 512];
    }
    P[(size_t)row * 512 + col] = f2bfu(acc);
}

// ---------------------------------------------------------------------------
// GEMM tile, BK=64 (r17, measured best): C[m0:+128, n0:+64] over K (N=512).
// 512 thr, 8 waves 4m x 2n (wave 32x32, acc 2x2). A LDS [128][72] u16;
// B LDS [64][72] 8-chunk rotate swizzle. Double-buffered, 1 barrier/step.
// ---------------------------------------------------------------------------
#define GEMM_KLOOP_BK64                                                        \
    FETCH(0)                                                                   \
    STORE(0)                                                                   \
    FETCH(64)                                                                  \
    __syncthreads();                                                           \
    int p = 0;                                                                 \
    for (int k0 = 0; k0 < K; k0 += 64) {                                       \
        if (k0 + 64 < K) {                                                     \
            STORE(p ^ 1)                                                       \
            if (k0 + 128 < K) FETCH(k0 + 128)                                  \
        }                                                                      \
        const u16* Ap  = As0 + p * 9216;                                       \
        const u16* Bp2 = Bs0 + p * 4608;                                       \
        short8 af0[2], af1[2], bf0[2], bf1[2];                                 \
        _Pragma("unroll")                                                      \
        for (int i = 0; i < 2; ++i) {                                          \
            af0[i] = *(const short8*)&Ap[(wm + i * 16 + lm) * 72 + kq * 8];    \
            af1[i] = *(const short8*)&Ap[(wm + i * 16 + lm) * 72 + 32 + kq * 8];\
        }                                                                      \
        _Pragma("unroll")                                                      \
        for (int j = 0; j < 2; ++j) {                                          \
            const int n = wn + j * 16 + lm;                                    \
            bf0[j] = *(const short8*)&Bp2[n * 72 + ((kq + (n >> 3)) & 7) * 8]; \
            bf1[j] = *(const short8*)&Bp2[n * 72 + ((4 + kq + (n >> 3)) & 7) * 8];\
        }                                                                      \
        _Pragma("unroll")                                                      \
        for (int i = 0; i < 2; ++i)                                            \
            _Pragma("unroll")                                                  \
            for (int j = 0; j < 2; ++j) {                                      \
                acc[i][j] = __builtin_amdgcn_mfma_f32_16x16x32_bf16(           \
                    af0[i], bf0[j], acc[i][j], 0, 0, 0);                       \
                acc[i][j] = __builtin_amdgcn_mfma_f32_16x16x32_bf16(           \
                    af1[i], bf1[j], acc[i][j], 0, 0, 0);                       \
            }                                                                  \
        if (k0 + 64 < K) __syncthreads();                                      \
        p ^= 1;                                                                \
    }

#define GEMM_FETCH_STORE_BK64                                                  \
    uint4 ra0, ra1, rbb;                                                       \
    float4 rf0, rf1;                                                           \
    (void)rf0; (void)rf1;

#define FETCH(k0)                                                             \
    {                                                                         \
        const int kg = (k0) + ac;                                             \
        const u16* base = (kg < K1) ? (A + kg) : (A2 + (kg - K1));            \
        ra0 = *(const uint4*)(base + (size_t)(m0 + ar) * 512);                \
        ra1 = *(const uint4*)(base + (size_t)(m0 + ar + 64) * 512);           \
        if constexpr (ISBF) {                                                 \
            rbb = *(const uint4*)(Bb + (size_t)((k0) + bkr) * 512 + n0 + nb); \
        } else {                                                              \
            const float* Bp_ = Bf + (size_t)((k0) + bkr) * 512 + n0 + nb;     \
            rf0 = *(const float4*)(Bp_ + 0);                                  \
            rf1 = *(const float4*)(Bp_ + 4);                                  \
        }                                                                     \
    }

#define STORE(pp)                                                             \
    {                                                                         \
        *(uint4*)&As0[(pp) * 9216 + ar * 72 + ac] = ra0;                      \
        *(uint4*)&As0[(pp) * 9216 + (ar + 64) * 72 + ac] = ra1;               \
        u16 bvals[8];                                                         \
        if constexpr (ISBF) {                                                 \
            union { uint4 v; u16 s[8]; } ub; ub.v = rbb;                      \
            _Pragma("unroll")                                                 \
            for (int i = 0; i < 8; ++i) bvals[i] = ub.s[i];                   \
        } else {                                                              \
            bvals[0] = f2bfu(rf0.x); bvals[1] = f2bfu(rf0.y);                 \
            bvals[2] = f2bfu(rf0.z); bvals[3] = f2bfu(rf0.w);                 \
            bvals[4] = f2bfu(rf1.x); bvals[5] = f2bfu(rf1.y);                 \
            bvals[6] = f2bfu(rf1.z); bvals[7] = f2bfu(rf1.w);                 \
        }                                                                     \
        const int slot_ = (((bkr >> 3) + jn) & 7) * 8 + (bkr & 7);            \
        _Pragma("unroll")                                                     \
        for (int i = 0; i < 8; ++i)                                           \
            Bs0[(pp) * 4608 + (nb + i) * 72 + slot_] = bvals[i];              \
    }

template<bool ISBF>
__device__ __forceinline__ void gemm_tile(
    const u16* __restrict__ A, const u16* __restrict__ A2, const int K1,
    const void* __restrict__ Bv, const void* __restrict__ biasv,
    u16* __restrict__ C, const int K, const int m0, const int n0,
    u16* __restrict__ As0, u16* __restrict__ Bs0)
{
    const int tid  = threadIdx.x;          // 0..511
    const int lane = tid & 63;
    const int wid = tid >> 6;              // 0..7
    const int wm  = (wid & 3) * 32;
    const int wn  = (wid >> 2) * 32;
    const int ar  = tid >> 3;              // 0..63 (A rows; also +64)
    const int ac  = (tid & 7) * 8;         // k-col within BK=64
    const int bkr = tid >> 3;              // 0..63 B k-row
    const int jn  = tid & 7;
    const int nb  = jn * 8;
    const int lm = lane & 15;
    const int kq = lane >> 4;

    const u16*   Bb = (const u16*)Bv;
    const float* Bf = (const float*)Bv;

    f32x4 acc[2][2];
    #pragma unroll
    for (int i = 0; i < 2; ++i)
        #pragma unroll
        for (int j = 0; j < 2; ++j)
            acc[i][j] = (f32x4){0.f, 0.f, 0.f, 0.f};

    GEMM_FETCH_STORE_BK64
    GEMM_KLOOP_BK64

    // epilogue: bias + tanh + bf16 store
    #pragma unroll
    for (int j = 0; j < 2; ++j) {
        const int n = n0 + wn + j * 16 + lm;
        const float bsv = ISBF ? bfu2f(((const u16*)biasv)[n])
                               : ((const float*)biasv)[n];
        #pragma unroll
        for (int i = 0; i < 2; ++i) {
            #pragma unroll
            for (int r = 0; r < 4; ++r) {
                const int m = m0 + wm + i * 16 + kq * 4 + r;
                C[(size_t)m * 512 + n] = f2bfu(fast_tanh(acc[i][j][r] + bsv));
            }
        }
    }
}

__global__ __launch_bounds__(512, 4) void gemm_mfma(
    const u16* __restrict__ A, const u16* __restrict__ A2, int K1,
    const void* __restrict__ B, const void* __restrict__ bias,
    u16* __restrict__ C, int K,
    const u16* __restrict__ Wdet, const unsigned int* __restrict__ Mdet)
{
    __shared__ __align__(16) u16 As[2 * 128 * 72];   // 36.9 KB
    __shared__ __align__(16) u16 Bs[2 * 64 * 72];    // 18.4 KB
    __shared__ int s_flags;

    if (threadIdx.x < 64) {
        int fl = detect_wave(Wdet, Mdet, threadIdx.x);
        if (threadIdx.x == 0) s_flags = fl;
    }
    __syncthreads();
    const int m0 = blockIdx.x * 128;
    const int n0 = blockIdx.y * 64;
    if (s_flags & 1) gemm_tile<true >(A, A2, K1, B, bias, C, K, m0, n0, As, Bs);
    else             gemm_tile<false>(A, A2, K1, B, bias, C, K, m0, n0, As, Bs);
}

// ---------------------------------------------------------------------------
// Kernel 3: GEMM3 + logits (r17). H kept in regs; logits via shfl-reduce
// over lm lanes + f32 atomicAdd into zeroed d_out.
// ---------------------------------------------------------------------------
template<bool ISBF>
__device__ __forceinline__ void g3_body(
    const u16* __restrict__ A, const u16* __restrict__ A2, const int K1,
    const void* __restrict__ Bv, const void* __restrict__ biasv,
    const void* __restrict__ w2v, const void* __restrict__ cb2v,
    float* __restrict__ outp, const int K,
    u16* __restrict__ As0, u16* __restrict__ Bs0)
{
    const int tid  = threadIdx.x;
    const int lane = tid & 63;
    const int wid = tid >> 6;
    const int wm  = (wid & 3) * 32;
    const int wn  = (wid >> 2) * 32;
    const int ar  = tid >> 3;
    const int ac  = (tid & 7) * 8;
    const int bkr = tid >> 3;
    const int jn  = tid & 7;
    const int nb  = jn * 8;
    const int lm = lane & 15;
    const int kq = lane >> 4;
    const int m0 = (blockIdx.x & 31) * 128;
    const int n0 = (blockIdx.x >> 5) * 64;

    const u16*   Bb = (const u16*)Bv;
    const float* Bf = (const float*)Bv;

    f32x4 acc[2][2];
    #pragma unroll
    for (int i = 0; i < 2; ++i)
        #pragma unroll
        for (int j = 0; j < 2; ++j)
            acc[i][j] = (f32x4){0.f, 0.f, 0.f, 0.f};

    GEMM_FETCH_STORE_BK64
    GEMM_KLOOP_BK64

    // epilogue: H = tanh(acc + cb1[n]); logits partials; lm-reduce; atomics
    float lg[2][4][3];
    #pragma unroll
    for (int i = 0; i < 2; ++i)
        #pragma unroll
        for (int r = 0; r < 4; ++r)
            #pragma unroll
            for (int l = 0; l < 3; ++l) lg[i][r][l] = 0.f;

    #pragma unroll
    for (int j = 0; j < 2; ++j) {
        const int n = n0 + wn + j * 16 + lm;
        const float bsv = ISBF ? bfu2f(((const u16*)biasv)[n])
                               : ((const float*)biasv)[n];
        float wc[3];
        #pragma unroll
        for (int l = 0; l < 3; ++l)
            wc[l] = ISBF ? bfu2f(((const u16*)w2v)[n * 3 + l])
                         : ((const float*)w2v)[n * 3 + l];
        #pragma unroll
        for (int i = 0; i < 2; ++i)
            #pragma unroll
            for (int r = 0; r < 4; ++r) {
                const float h = fast_tanh(acc[i][j][r] + bsv);
                #pragma unroll
                for (int l = 0; l < 3; ++l) lg[i][r][l] += h * wc[l];
            }
    }
    #pragma unroll
    for (int off = 1; off <= 8; off <<= 1)
        #pragma unroll
        for (int i = 0; i < 2; ++i)
            #pragma unroll
            for (int r = 0; r < 4; ++r)
                #pragma unroll
                for (int l = 0; l < 3; ++l)
                    lg[i][r][l] += __shfl_xor(lg[i][r][l], off);

    if (lm == 0) {
        const bool addb = (n0 == 0) && (wn == 0);   // exactly one per (m,l)
        float cb[3];
        #pragma unroll
        for (int l = 0; l < 3; ++l)
            cb[l] = ISBF ? bfu2f(((const u16*)cb2v)[l])
                         : ((const float*)cb2v)[l];
        #pragma unroll
        for (int i = 0; i < 2; ++i)
            #pragma unroll
            for (int r = 0; r < 4; ++r) {
                const int m = m0 + wm + i * 16 + kq * 4 + r;
                #pragma unroll
                for (int l = 0; l < 3; ++l) {
                    float v = lg[i][r][l];
                    if (addb) v += cb[l];
                    atomicAdd(&outp[m * 3 + l], v);
                }
            }
    }
}

__global__ __launch_bounds__(512, 4) void gemm3_logits(
    const u16* __restrict__ A, const u16* __restrict__ A2, int K1,
    const void* __restrict__ B, const void* __restrict__ bias,
    const void* __restrict__ w2, const void* __restrict__ cb2,
    float* __restrict__ out, int K,
    const u16* __restrict__ Wdet, const unsigned int* __restrict__ Mdet)
{
    __shared__ __align__(16) u16 As[2 * 128 * 72];
    __shared__ __align__(16) u16 Bs[2 * 64 * 72];
    __shared__ int s_flags;

    if (threadIdx.x < 64) {
        int fl = detect_wave(Wdet, Mdet, threadIdx.x);
        if (threadIdx.x == 0) s_flags = fl;
    }
    __syncthreads();
    if (s_flags & 1)
        g3_body<true >(A, A2, K1, B, bias, w2, cb2, out, K, As, Bs);
    else
        g3_body<false>(A, A2, K1, B, bias, w2, cb2, out, K, As, Bs);
}

// ---------------------------------------------------------------------------
extern "C" void kernel_launch(void* const* d_in, const int* in_sizes, int n_in,
                              void* d_out, int out_size, void* d_ws, size_t ws_size,
                              hipStream_t stream)
{
    const int* ids_a  = (const int*)d_in[0];
    const int* ids_b  = (const int*)d_in[1];
    const void* mask_a = d_in[2];
    const void* mask_b = d_in[3];
    const void* W_emb  = d_in[4];
    const void* enc_w1 = d_in[5];
    const void* enc_b1 = d_in[6];
    const void* enc_w2 = d_in[7];
    const void* enc_b2 = d_in[8];
    const void* cls_w1 = d_in[9];
    const void* cls_b1 = d_in[10];
    const void* cls_w2 = d_in[11];
    const void* cls_b2 = d_in[12];

    const u16* Wdet = (const u16*)W_emb;
    const unsigned int* Mdet = (const unsigned int*)mask_a;

    u16* buf0 = (u16*)d_ws;                          // 8192*512 bf16 = 8 MB
    u16* buf1 = buf0 + (size_t)8192 * 512;           // 8 MB
    float* outp = (float*)d_out;

    // P -> buf0 (rows 0..4095 side a, 4096..8191 side b); also zeroes d_out.
    // 65536 blocks: row = bid>>3, col-slice = bid&7 (XCD-resident table slice)
    pool_kernel<<<65536, 64, 0, stream>>>(ids_a, ids_b, mask_a, mask_b,
                                          W_emb, buf0, outp, Mdet);

    // X1 = tanh(P @ w1 + b1) -> buf1
    gemm_mfma<<<dim3(64, 8), 512, 0, stream>>>(
        buf0, buf0, 512, enc_w1, enc_b1, buf1, 512, Wdet, Mdet);

    // X2 = tanh(X1 @ w2 + b2) -> buf0
    gemm_mfma<<<dim3(64, 8), 512, 0, stream>>>(
        buf1, buf1, 512, enc_w2, enc_b2, buf0, 512, Wdet, Mdet);

    // logits = tanh([va|vb]@cw1+cb1) @ cw2 + cb2 -> d_out (f32, atomics)
    gemm3_logits<<<256, 512, 0, stream>>>(
        buf0, buf0 + (size_t)4096 * 512, 512, cls_w1, cls_b1,
        cls_w2, cls_b2, outp, 1024, Wdet, Mdet);
}